// Round 12
// baseline (297.431 us; speedup 1.0000x reference)
//
#include <hip/hip_runtime.h>
#include <hip/hip_bf16.h>
#include <math.h>

#define SEQ    2048
#define NBTOT  16
#define NCH    64
#define CHL    32            // NCH*CHL == SEQ

#define L2E 1.4426950408889634f

typedef __attribute__((ext_vector_type(8))) __bf16 bf16x8;
typedef __attribute__((ext_vector_type(4))) float f32x4;
typedef __attribute__((ext_vector_type(2))) float f32x2;

#define GLOAD16(gp, lp)                                                   \
  __builtin_amdgcn_global_load_lds(                                       \
      (const __attribute__((address_space(1))) unsigned int*)(gp),        \
      (__attribute__((address_space(3))) unsigned int*)(lp), 16, 0, 0)

__device__ __forceinline__ float exp2_(float x) {
  return __builtin_amdgcn_exp2f(x);
}
__device__ __forceinline__ float silu_(float x) {
  return x * __builtin_amdgcn_rcpf(1.f + exp2_(-x * L2E));
}
__device__ __forceinline__ float softplus_(float x) {
  return fmaxf(x, 0.f) + __logf(1.f + exp2_(-fabsf(x) * L2E));
}
__device__ __forceinline__ float wsum_(float v) {
#pragma unroll
  for (int off = 32; off > 0; off >>= 1) v += __shfl_xor(v, off, 64);
  return v;
}
// Bijective XCD-chunk swizzle (nwg mult of 8) — pipeline-consistent row->XCD.
__device__ __forceinline__ int xcdswz_(int bid, int nwg) {
  return (bid & 7) * (nwg >> 3) + (bid >> 3);
}
// p[k] = {e1^(2k+1), e1^(2k+2)}: 2 squares + 7 pk_mul, depth 4
__device__ __forceinline__ void powpairs_(float e1, f32x2 p[8]) {
  float e2 = e1 * e1;
  f32x2 p0; p0.x = e1; p0.y = e2;
  f32x2 s2; s2.x = e2; s2.y = e2;
  f32x2 s4 = s2 * s2;
  f32x2 s8 = s4 * s4;
  p[0] = p0;      p[1] = p0 * s2; p[2] = p0 * s4; p[3] = p[1] * s4;
  p[4] = p0 * s8; p[5] = p[1] * s8; p[6] = p[2] * s8; p[7] = p[3] * s8;
}

// ---------------------------------------------------------------------------
// bf16 MFMA GEMM (m97 structure) + XCD-chunk swizzle + LDS-bounce epilogue.
// ---------------------------------------------------------------------------
template <bool BIAS, bool RELU, bool RES, bool RESB, bool BF16OUT, int NTLOG>
__global__ __launch_bounds__(256) void gemm_bf16(
    const __hip_bfloat16* __restrict__ A, const __hip_bfloat16* __restrict__ W,
    const float* __restrict__ bias, const float* __restrict__ res,
    const __hip_bfloat16* __restrict__ resb,
    __hip_bfloat16* __restrict__ Cb, int N, int K) {
  __shared__ __align__(16) char ShRaw[36864];
  short* Als = reinterpret_cast<short*>(ShRaw);
  short* Bls = Als + 8192;
  const int tid = threadIdx.x;
  const int lane = tid & 63;
  const int wid = tid >> 6;
  const int swz = xcdswz_(blockIdx.x, gridDim.x);
  const int m0 = (swz >> NTLOG) * 128;
  const int n0 = (swz & ((1 << NTLOG) - 1)) * 128;
  const int wm = (wid >> 1) * 64;
  const int wn = (wid & 1) * 64;
  const int lr = lane & 15;
  const int lk = lane >> 4;  // 0..3

  f32x4 acc[4][4];
#pragma unroll
  for (int m = 0; m < 4; ++m)
#pragma unroll
    for (int n = 0; n < 4; ++n) acc[m][n] = (f32x4){0.f, 0.f, 0.f, 0.f};

  const int srow = wid * 32 + (lane >> 3);
  const int scol = (lane & 7) * 8;
  const __hip_bfloat16* Ag = A + (size_t)(m0 + srow) * K + scol;
  const __hip_bfloat16* Wg = W + (size_t)(n0 + srow) * K + scol;
  short* Alb = Als + wid * 2048;
  short* Blb = Bls + wid * 2048;

  for (int kt = 0; kt < K; kt += 64) {
#pragma unroll
    for (int i = 0; i < 4; ++i) {
      GLOAD16(Ag + (size_t)(i * 8) * K + kt, Alb + i * 512);
      GLOAD16(Wg + (size_t)(i * 8) * K + kt, Blb + i * 512);
    }
    __syncthreads();
    const bf16x8* Af = reinterpret_cast<const bf16x8*>(Als);
    const bf16x8* Bf = reinterpret_cast<const bf16x8*>(Bls);
#pragma unroll
    for (int ks = 0; ks < 2; ++ks) {
      bf16x8 av[4], bv[4];
#pragma unroll
      for (int m = 0; m < 4; ++m)
        av[m] = Af[(wm + m * 16 + lr) * 8 + ks * 4 + lk];
#pragma unroll
      for (int n = 0; n < 4; ++n)
        bv[n] = Bf[(wn + n * 16 + lr) * 8 + ks * 4 + lk];
#pragma unroll
      for (int m = 0; m < 4; ++m)
#pragma unroll
        for (int n = 0; n < 4; ++n)
          acc[m][n] = __builtin_amdgcn_mfma_f32_16x16x32_bf16(
              av[m], bv[n], acc[m][n], 0, 0, 0);
    }
    __syncthreads();  // staging LDS dead after -> epilogue reuse
  }

  __hip_bfloat16* epi = reinterpret_cast<__hip_bfloat16*>(ShRaw) + wid * 4608;
#pragma unroll
  for (int n = 0; n < 4; ++n) {
    int col = n0 + wn + n * 16 + lr;
    float bval = BIAS ? bias[col] : 0.f;
#pragma unroll
    for (int m = 0; m < 4; ++m) {
      int lrow = m * 16 + lk * 4;
#pragma unroll
      for (int r = 0; r < 4; ++r) {
        float v = acc[m][n][r];
        if (BIAS) v += bval;
        if (RES) v += res[(size_t)(m0 + wm + lrow + r) * N + col];
        if (RESB)
          v += __bfloat162float(resb[(size_t)(m0 + wm + lrow + r) * N + col]);
        if (RELU) v = fmaxf(v, 0.f);
        epi[(lrow + r) * 72 + n * 16 + lr] = __float2bfloat16(v);
      }
    }
  }
  const int lr8 = (lane & 7) * 8;
  const int lrw = lane >> 3;
  const size_t obase = (size_t)(m0 + wm) * N + n0 + wn + lr8;
#pragma unroll
  for (int j = 0; j < 8; ++j) {
    int row = j * 8 + lrw;
    int4 vv = *reinterpret_cast<const int4*>(epi + row * 72 + lr8);
    *reinterpret_cast<int4*>(&Cb[obase + (size_t)row * N]) = vv;
  }
}

// ---------------------------------------------------------------------------
// x_proj GEMM with conv+SiLU fused into A staging (registers -> ds_write).
// A = silu(depthwise_conv4(xz[:, 0:512])); W: 128x512 (zero-padded); N=48 out.
// xz row stride 1024 bf16. C f32 (M,48).
// ---------------------------------------------------------------------------
__global__ __launch_bounds__(256) void gemm_xproj(
    const __hip_bfloat16* __restrict__ xz, const __hip_bfloat16* __restrict__ W,
    const float* __restrict__ cw, const float* __restrict__ cb,
    float* __restrict__ C) {
  __shared__ __align__(16) short Als[128 * 64];
  __shared__ __align__(16) short Bls[128 * 64];
  const int tid = threadIdx.x;
  const int lane = tid & 63;
  const int wid = tid >> 6;
  const int m0 = xcdswz_(blockIdx.x, gridDim.x) * 128;
  const int wm = (wid >> 1) * 64;
  const int wn = (wid & 1) * 64;
  const int lr = lane & 15;
  const int lk = lane >> 4;

  f32x4 acc[4][4];
#pragma unroll
  for (int m = 0; m < 4; ++m)
#pragma unroll
    for (int n = 0; n < 4; ++n) acc[m][n] = (f32x4){0.f, 0.f, 0.f, 0.f};

  const int srow = wid * 32 + (lane >> 3);
  const int scol = (lane & 7) * 8;
  const __hip_bfloat16* Wg = W + (size_t)srow * 512 + scol;
  short* Alb = Als + wid * 2048;
  short* Blb = Bls + wid * 2048;
  const float4* cw4 = reinterpret_cast<const float4*>(cw);

  for (int kt = 0; kt < 512; kt += 64) {
    // B staging (weights) via global_load_lds
#pragma unroll
    for (int i = 0; i < 4; ++i)
      GLOAD16(Wg + (size_t)(i * 8) * 512 + kt, Blb + i * 512);
    // A staging: conv+silu from xz in registers, ds_write
#pragma unroll
    for (int i = 0; i < 4; ++i) {
      int rr = m0 + srow + i * 8;
      int l = rr & (SEQ - 1);
      const __hip_bfloat16* pz = xz + (size_t)rr * 1024 + kt + scol;
      union U8 { int4 v; __hip_bfloat16 h[8]; } x0, x1, x2, x3, o;
      const int4 z4 = make_int4(0, 0, 0, 0);
      x3.v = *reinterpret_cast<const int4*>(pz);
      x2.v = (l >= 1) ? *reinterpret_cast<const int4*>(pz - 1024) : z4;
      x1.v = (l >= 2) ? *reinterpret_cast<const int4*>(pz - 2048) : z4;
      x0.v = (l >= 3) ? *reinterpret_cast<const int4*>(pz - 3072) : z4;
#pragma unroll
      for (int j = 0; j < 8; ++j) {
        int ch = kt + scol + j;
        float4 w = cw4[ch];
        float a = cb[ch];
        a = fmaf(w.x, __bfloat162float(x0.h[j]), a);
        a = fmaf(w.y, __bfloat162float(x1.h[j]), a);
        a = fmaf(w.z, __bfloat162float(x2.h[j]), a);
        a = fmaf(w.w, __bfloat162float(x3.h[j]), a);
        o.h[j] = __float2bfloat16(silu_(a));
      }
      *reinterpret_cast<int4*>(Alb + i * 512 + lane * 8) = o.v;
    }
    __syncthreads();
    const bf16x8* Af = reinterpret_cast<const bf16x8*>(Als);
    const bf16x8* Bf = reinterpret_cast<const bf16x8*>(Bls);
#pragma unroll
    for (int ks = 0; ks < 2; ++ks) {
      bf16x8 av[4], bv[4];
#pragma unroll
      for (int m = 0; m < 4; ++m)
        av[m] = Af[(wm + m * 16 + lr) * 8 + ks * 4 + lk];
#pragma unroll
      for (int n = 0; n < 4; ++n)
        bv[n] = Bf[(wn + n * 16 + lr) * 8 + ks * 4 + lk];
#pragma unroll
      for (int m = 0; m < 4; ++m)
#pragma unroll
        for (int n = 0; n < 4; ++n)
          acc[m][n] = __builtin_amdgcn_mfma_f32_16x16x32_bf16(
              av[m], bv[n], acc[m][n], 0, 0, 0);
    }
    __syncthreads();
  }

#pragma unroll
  for (int n = 0; n < 4; ++n) {
    int col = wn + n * 16 + lr;
    if (col >= 48) continue;
#pragma unroll
    for (int m = 0; m < 4; ++m) {
      int row0 = m0 + wm + m * 16 + lk * 4;
#pragma unroll
      for (int r = 0; r < 4; ++r)
        C[(size_t)(row0 + r) * 48 + col] = acc[m][n][r];
    }
  }
}

// ---------------------------------------------------------------------------
__global__ __launch_bounds__(256) void cast_bf16_k(
    const float* __restrict__ src, __hip_bfloat16* __restrict__ dst, int n4) {
  int i = xcdswz_(blockIdx.x, gridDim.x) * 256 + threadIdx.x;
  if (i >= n4) return;
  float4 v = reinterpret_cast<const float4*>(src)[i];
  union { __hip_bfloat16 h[4]; short4 s4; } u;
  u.h[0] = __float2bfloat16(v.x); u.h[1] = __float2bfloat16(v.y);
  u.h[2] = __float2bfloat16(v.z); u.h[3] = __float2bfloat16(v.w);
  reinterpret_cast<short4*>(dst)[i] = u.s4;
}

__global__ __launch_bounds__(256) void pad_wx_k(
    const float* __restrict__ src, __hip_bfloat16* __restrict__ dst) {
  int i = blockIdx.x * 256 + threadIdx.x;
  int row = i >> 7;
  union { __hip_bfloat16 h[4]; short4 s4; } u;
  if (row < 48) {
    float4 v = reinterpret_cast<const float4*>(src)[i];
    u.h[0] = __float2bfloat16(v.x); u.h[1] = __float2bfloat16(v.y);
    u.h[2] = __float2bfloat16(v.z); u.h[3] = __float2bfloat16(v.w);
  } else {
    u.h[0] = u.h[1] = u.h[2] = u.h[3] = __float2bfloat16(0.f);
  }
  reinterpret_cast<short4*>(dst)[i] = u.s4;
}

// ---------------------------------------------------------------------------
// Chunked selective scan; u = silu(conv(xz[:, d])) computed inline via a
// rolling 4-tap window (3 guarded preloads at chunk start, 1 load/step).
// ---------------------------------------------------------------------------
__global__ __launch_bounds__(256) void scan_p1(
    const __hip_bfloat16* __restrict__ xz, const float* __restrict__ xdbl,
    const float* __restrict__ A_log, const float* __restrict__ wdt,
    const float* __restrict__ bdt, const float* __restrict__ cw,
    const float* __restrict__ cb, float* __restrict__ dlsum,
    __hip_bfloat16* __restrict__ hp, __hip_bfloat16* __restrict__ deltab) {
  const int w = xcdswz_(blockIdx.x, gridDim.x);  // b*128 + c*2 + h
  const int b = w >> 7;
  const int c = (w >> 1) & 63;
  const int d = ((w & 1) << 8) + threadIdx.x;
  const int l0 = c * CHL;
  float A2[16];
  f32x2 w2[8];
  {
    const float4* aq = reinterpret_cast<const float4*>(&A_log[d * 16]);
    const f32x2* wq = reinterpret_cast<const f32x2*>(&wdt[d * 16]);
#pragma unroll
    for (int q = 0; q < 4; ++q) {
      float4 v = aq[q];
      A2[q * 4 + 0] = -exp2_(v.x * L2E) * L2E;
      A2[q * 4 + 1] = -exp2_(v.y * L2E) * L2E;
      A2[q * 4 + 2] = -exp2_(v.z * L2E) * L2E;
      A2[q * 4 + 3] = -exp2_(v.w * L2E) * L2E;
    }
#pragma unroll
    for (int k = 0; k < 8; ++k) w2[k] = wq[k];
  }
  bool chainok = true;
#pragma unroll
  for (int n = 1; n < 16; ++n)
    chainok = chainok &&
              (fabsf(A2[n] - (float)(n + 1) * A2[0]) <=
               1e-4f * (float)(n + 1) * fabsf(A2[0]));
  const float bdtd = bdt[d];
  const float nL = A2[0];
  // conv state
  const float4 cwv = reinterpret_cast<const float4*>(cw)[d];
  const float cbv = cb[d];
  const __hip_bfloat16* zrow = xz + (size_t)(b * SEQ + l0) * 1024 + d;
  float xm1 = (l0 >= 1) ? __bfloat162float(zrow[-1024]) : 0.f;
  float xm2 = (l0 >= 2) ? __bfloat162float(zrow[-2048]) : 0.f;
  float xm3 = (l0 >= 3) ? __bfloat162float(zrow[-3072]) : 0.f;
  f32x2 h2[8];
#pragma unroll
  for (int k = 0; k < 8; ++k) h2[k] = (f32x2){0.f, 0.f};
  float dls = 0.f;
  size_t base = (size_t)(b * SEQ + l0) * 512 + d;
  const float* rowp = xdbl + (size_t)(b * SEQ + l0) * 48;
  if (chainok) {
#pragma unroll 4
    for (int i = 0; i < CHL; ++i) {
      float xn = __bfloat162float(zrow[(size_t)i * 1024]);
      float ua = fmaf(cwv.w, xn, fmaf(cwv.z, xm1,
                  fmaf(cwv.y, xm2, fmaf(cwv.x, xm3, cbv))));
      float ul = silu_(ua);
      xm3 = xm2; xm2 = xm1; xm1 = xn;
      const f32x2* r2 = reinterpret_cast<const f32x2*>(rowp + i * 48);
      f32x2 acc2; acc2.x = bdtd; acc2.y = 0.f;
#pragma unroll
      for (int k = 0; k < 8; ++k)
        acc2 = __builtin_elementwise_fma(r2[k], w2[k], acc2);
      float dl = softplus_(acc2.x + acc2.y);
      deltab[base + (size_t)i * 512] = __float2bfloat16(dl);
      dls += dl;
      float du = dl * ul;
      f32x2 p[8];
      powpairs_(exp2_(dl * nL), p);
      f32x2 du2; du2.x = du; du2.y = du;
#pragma unroll
      for (int k = 0; k < 8; ++k)
        h2[k] = __builtin_elementwise_fma(p[k], h2[k], du2 * r2[8 + k]);
    }
  } else {
#pragma unroll 2
    for (int i = 0; i < CHL; ++i) {
      float xn = __bfloat162float(zrow[(size_t)i * 1024]);
      float ua = fmaf(cwv.w, xn, fmaf(cwv.z, xm1,
                  fmaf(cwv.y, xm2, fmaf(cwv.x, xm3, cbv))));
      float ul = silu_(ua);
      xm3 = xm2; xm2 = xm1; xm1 = xn;
      const f32x2* r2 = reinterpret_cast<const f32x2*>(rowp + i * 48);
      f32x2 acc2; acc2.x = bdtd; acc2.y = 0.f;
#pragma unroll
      for (int k = 0; k < 8; ++k)
        acc2 = __builtin_elementwise_fma(r2[k], w2[k], acc2);
      float dl = softplus_(acc2.x + acc2.y);
      deltab[base + (size_t)i * 512] = __float2bfloat16(dl);
      dls += dl;
      float du = dl * ul;
      f32x2 du2; du2.x = du; du2.y = du;
#pragma unroll
      for (int k = 0; k < 8; ++k) {
        f32x2 a; a.x = exp2_(dl * A2[2 * k]); a.y = exp2_(dl * A2[2 * k + 1]);
        h2[k] = __builtin_elementwise_fma(a, h2[k], du2 * r2[8 + k]);
      }
    }
  }
  size_t sc = (size_t)(b * NCH + c) * 512 + d;
  dlsum[sc] = dls;
  union { __hip_bfloat16 h[4]; short4 s4; } o0, o1, o2, o3;
#pragma unroll
  for (int j = 0; j < 2; ++j) {
    o0.h[2*j] = __float2bfloat16(h2[j].x);   o0.h[2*j+1] = __float2bfloat16(h2[j].y);
    o1.h[2*j] = __float2bfloat16(h2[2+j].x); o1.h[2*j+1] = __float2bfloat16(h2[2+j].y);
    o2.h[2*j] = __float2bfloat16(h2[4+j].x); o2.h[2*j+1] = __float2bfloat16(h2[4+j].y);
    o3.h[2*j] = __float2bfloat16(h2[6+j].x); o3.h[2*j+1] = __float2bfloat16(h2[6+j].y);
  }
  short4* hq = reinterpret_cast<short4*>(hp + sc * 16);
  hq[0] = o0.s4; hq[1] = o1.s4; hq[2] = o2.s4; hq[3] = o3.s4;
}

// In-place: Hc overwrites hp (in-thread read-before-write per idx).
__global__ __launch_bounds__(256) void scan_p2(
    __hip_bfloat16* hp, const float* __restrict__ dlsum,
    const float* __restrict__ A_log) {
  int g = xcdswz_(blockIdx.x, gridDim.x) * 256 + threadIdx.x;
  int b = g >> 13;
  int dn = g & 8191;
  int d = dn >> 4;
  float A2n = -exp2_(A_log[dn] * L2E) * L2E;
  float H = 0.f;
  for (int c = 0; c < NCH; ++c) {
    float ds = dlsum[(size_t)(b * NCH + c) * 512 + d];
    size_t idx = (size_t)(b * NCH + c) * 8192 + dn;
    float p = __bfloat162float(hp[idx]);
    float a = exp2_(A2n * ds);
    hp[idx] = __float2bfloat16(H);
    H = fmaf(a, H, p);
  }
}

__global__ __launch_bounds__(256) void scan_p3(
    const float* __restrict__ A_log,
    const __hip_bfloat16* __restrict__ deltab, const float* __restrict__ xdbl,
    const __hip_bfloat16* __restrict__ Hc, const float* __restrict__ Dp,
    const __hip_bfloat16* __restrict__ xz, const float* __restrict__ cw,
    const float* __restrict__ cb, __hip_bfloat16* __restrict__ y) {
  const int w = xcdswz_(blockIdx.x, gridDim.x);
  const int b = w >> 7;
  const int c = (w >> 1) & 63;
  const int d = ((w & 1) << 8) + threadIdx.x;
  const int l0 = c * CHL;
  float A2[16];
  {
    const float4* aq = reinterpret_cast<const float4*>(&A_log[d * 16]);
#pragma unroll
    for (int q = 0; q < 4; ++q) {
      float4 v = aq[q];
      A2[q * 4 + 0] = -exp2_(v.x * L2E) * L2E;
      A2[q * 4 + 1] = -exp2_(v.y * L2E) * L2E;
      A2[q * 4 + 2] = -exp2_(v.z * L2E) * L2E;
      A2[q * 4 + 3] = -exp2_(v.w * L2E) * L2E;
    }
  }
  bool chainok = true;
#pragma unroll
  for (int n = 1; n < 16; ++n)
    chainok = chainok &&
              (fabsf(A2[n] - (float)(n + 1) * A2[0]) <=
               1e-4f * (float)(n + 1) * fabsf(A2[0]));
  const float nL = A2[0];
  f32x2 h2[8];
  {
    const short4* hq =
        reinterpret_cast<const short4*>(Hc + ((size_t)(b * NCH + c) * 512 + d) * 16);
#pragma unroll
    for (int q = 0; q < 4; ++q) {
      union { short4 s4; __hip_bfloat16 h[4]; } iv;
      iv.s4 = hq[q];
      h2[2*q].x = __bfloat162float(iv.h[0]);
      h2[2*q].y = __bfloat162float(iv.h[1]);
      h2[2*q+1].x = __bfloat162float(iv.h[2]);
      h2[2*q+1].y = __bfloat162float(iv.h[3]);
    }
  }
  const float Dpd = Dp[d];
  const float4 cwv = reinterpret_cast<const float4*>(cw)[d];
  const float cbv = cb[d];
  const __hip_bfloat16* zrow = xz + (size_t)(b * SEQ + l0) * 1024 + d;
  float xm1 = (l0 >= 1) ? __bfloat162float(zrow[-1024]) : 0.f;
  float xm2 = (l0 >= 2) ? __bfloat162float(zrow[-2048]) : 0.f;
  float xm3 = (l0 >= 3) ? __bfloat162float(zrow[-3072]) : 0.f;
  size_t base = (size_t)(b * SEQ + l0) * 512 + d;
  const float* rowp = xdbl + (size_t)(b * SEQ + l0) * 48;
  const __hip_bfloat16* zp = zrow + 512;  // z = xz[:, 512+d]
  if (chainok) {
#pragma unroll 4
    for (int i = 0; i < CHL; ++i) {
      float xn = __bfloat162float(zrow[(size_t)i * 1024]);
      float ua = fmaf(cwv.w, xn, fmaf(cwv.z, xm1,
                  fmaf(cwv.y, xm2, fmaf(cwv.x, xm3, cbv))));
      float ul = silu_(ua);
      xm3 = xm2; xm2 = xm1; xm1 = xn;
      const f32x2* r2 = reinterpret_cast<const f32x2*>(rowp + i * 48);
      float dl = __bfloat162float(deltab[base + (size_t)i * 512]);
      float du = dl * ul;
      f32x2 p[8];
      powpairs_(exp2_(dl * nL), p);
      f32x2 du2; du2.x = du; du2.y = du;
      f32x2 yv2; yv2.x = 0.f; yv2.y = 0.f;
#pragma unroll
      for (int k = 0; k < 8; ++k) {
        h2[k] = __builtin_elementwise_fma(p[k], h2[k], du2 * r2[8 + k]);
        yv2 = __builtin_elementwise_fma(h2[k], r2[16 + k], yv2);
      }
      float yv = yv2.x + yv2.y;
      float zv = __bfloat162float(zp[(size_t)i * 1024]);
      y[base + (size_t)i * 512] =
          __float2bfloat16((yv + ul * Dpd) * silu_(zv));
    }
  } else {
#pragma unroll 2
    for (int i = 0; i < CHL; ++i) {
      float xn = __bfloat162float(zrow[(size_t)i * 1024]);
      float ua = fmaf(cwv.w, xn, fmaf(cwv.z, xm1,
                  fmaf(cwv.y, xm2, fmaf(cwv.x, xm3, cbv))));
      float ul = silu_(ua);
      xm3 = xm2; xm2 = xm1; xm1 = xn;
      const f32x2* r2 = reinterpret_cast<const f32x2*>(rowp + i * 48);
      float dl = __bfloat162float(deltab[base + (size_t)i * 512]);
      float du = dl * ul;
      f32x2 du2; du2.x = du; du2.y = du;
      f32x2 yv2; yv2.x = 0.f; yv2.y = 0.f;
#pragma unroll
      for (int k = 0; k < 8; ++k) {
        f32x2 a; a.x = exp2_(dl * A2[2 * k]); a.y = exp2_(dl * A2[2 * k + 1]);
        h2[k] = __builtin_elementwise_fma(a, h2[k], du2 * r2[8 + k]);
        yv2 = __builtin_elementwise_fma(h2[k], r2[16 + k], yv2);
      }
      float yv = yv2.x + yv2.y;
      float zv = __bfloat162float(zp[(size_t)i * 1024]);
      y[base + (size_t)i * 512] =
          __float2bfloat16((yv + ul * Dpd) * silu_(zv));
    }
  }
}

// ---------------------------------------------------------------------------
__global__ __launch_bounds__(256) void ln_k(
    const __hip_bfloat16* __restrict__ in, const float* __restrict__ g,
    const float* __restrict__ bb, __hip_bfloat16* __restrict__ outb) {
  int row = (xcdswz_(blockIdx.x, gridDim.x) * 256 + threadIdx.x) >> 6;
  int lane = threadIdx.x & 63;
  union { short4 s4; __hip_bfloat16 h[4]; } iv;
  iv.s4 = reinterpret_cast<const short4*>(in)[row * 64 + lane];
  float v0 = __bfloat162float(iv.h[0]), v1 = __bfloat162float(iv.h[1]);
  float v2 = __bfloat162float(iv.h[2]), v3 = __bfloat162float(iv.h[3]);
  float mu = wsum_(v0 + v1 + v2 + v3) * (1.f / 256.f);
  float a0 = v0 - mu, a1 = v1 - mu, a2 = v2 - mu, a3 = v3 - mu;
  float var = wsum_(a0 * a0 + a1 * a1 + a2 * a2 + a3 * a3) * (1.f / 256.f);
  float rs = __builtin_amdgcn_rsqf(var + 1e-5f);
  float4 gg = *reinterpret_cast<const float4*>(&g[lane * 4]);
  float4 bq = *reinterpret_cast<const float4*>(&bb[lane * 4]);
  union { __hip_bfloat16 h[4]; short4 s4; } u;
  u.h[0] = __float2bfloat16(a0 * rs * gg.x + bq.x);
  u.h[1] = __float2bfloat16(a1 * rs * gg.y + bq.y);
  u.h[2] = __float2bfloat16(a2 * rs * gg.z + bq.z);
  u.h[3] = __float2bfloat16(a3 * rs * gg.w + bq.w);
  reinterpret_cast<short4*>(outb)[row * 64 + lane] = u.s4;
}

// ---------------------------------------------------------------------------
__global__ __launch_bounds__(256) void final_k(
    const __hip_bfloat16* __restrict__ t2, const float* __restrict__ g2v,
    const float* __restrict__ b2v, const float* __restrict__ g3v,
    const float* __restrict__ b3v, const float* __restrict__ x,
    float* __restrict__ out) {
  int bx = xcdswz_(blockIdx.x, gridDim.x);
  int half = bx & 1, nv = (bx >> 1) & 31, b = bx >> 6;
  int wave = threadIdx.x >> 6, lane = threadIdx.x & 63;
  __shared__ float sh[32][257];
  float4 gg2 = *reinterpret_cast<const float4*>(&g2v[lane * 4]);
  float4 bb2 = *reinterpret_cast<const float4*>(&b2v[lane * 4]);
  float4 gg3 = *reinterpret_cast<const float4*>(&g3v[lane * 4]);
  float4 bb3 = *reinterpret_cast<const float4*>(&b3v[lane * 4]);
#pragma unroll
  for (int i = 0; i < 8; ++i) {
    int pn = wave * 8 + i;
    int r = ((b * 32 + nv) << 6) + (half << 5) + pn;
    union { short4 s4; __hip_bfloat16 h[4]; } iv;
    iv.s4 = reinterpret_cast<const short4*>(t2)[r * 64 + lane];
    float v0 = __bfloat162float(iv.h[0]), v1 = __bfloat162float(iv.h[1]);
    float v2 = __bfloat162float(iv.h[2]), v3 = __bfloat162float(iv.h[3]);
    float mu = wsum_(v0 + v1 + v2 + v3) * (1.f / 256.f);
    float a0 = v0 - mu, a1 = v1 - mu, a2 = v2 - mu, a3 = v3 - mu;
    float var = wsum_(a0 * a0 + a1 * a1 + a2 * a2 + a3 * a3) * (1.f / 256.f);
    float rs = __builtin_amdgcn_rsqf(var + 1e-5f);
    a0 = a0 * rs * gg2.x + bb2.x; a1 = a1 * rs * gg2.y + bb2.y;
    a2 = a2 * rs * gg2.z + bb2.z; a3 = a3 * rs * gg2.w + bb2.w;
    mu = wsum_(a0 + a1 + a2 + a3) * (1.f / 256.f);
    float c0 = a0 - mu, c1 = a1 - mu, c2 = a2 - mu, c3 = a3 - mu;
    var = wsum_(c0 * c0 + c1 * c1 + c2 * c2 + c3 * c3) * (1.f / 256.f);
    rs = __builtin_amdgcn_rsqf(var + 1e-5f);
    sh[pn][lane * 4 + 0] = c0 * rs * gg3.x + bb3.x;
    sh[pn][lane * 4 + 1] = c1 * rs * gg3.y + bb3.y;
    sh[pn][lane * 4 + 2] = c2 * rs * gg3.z + bb3.z;
    sh[pn][lane * 4 + 3] = c3 * rs * gg3.w + bb3.w;
  }
  __syncthreads();
  int pnl = threadIdx.x & 31;
  int dbase = threadIdx.x >> 5;
  size_t obase = (size_t)((b * 32 + nv) * 256) * 64 + (half << 5) + pnl;
#pragma unroll
  for (int k = 0; k < 32; ++k) {
    int dd = dbase + (k << 3);
    size_t oi = obase + (size_t)dd * 64;
    out[oi] = sh[pnl][dd] + x[oi];
  }
}

// ---------------------------------------------------------------------------
extern "C" void kernel_launch(void* const* d_in, const int* in_sizes, int n_in,
                              void* d_out, int out_size, void* d_ws,
                              size_t ws_size, hipStream_t stream) {
  const float* x    = (const float*)d_in[0];
  const float* w_in = (const float*)d_in[1];
  const float* b_in = (const float*)d_in[2];
  const float* cw   = (const float*)d_in[3];
  const float* cb   = (const float*)d_in[4];
  const float* wx   = (const float*)d_in[5];
  const float* wdt  = (const float*)d_in[6];
  const float* bdt  = (const float*)d_in[7];
  const float* alog = (const float*)d_in[8];
  const float* Dp   = (const float*)d_in[9];
  const float* wout = (const float*)d_in[10];
  const float* g1   = (const float*)d_in[11];
  const float* b1   = (const float*)d_in[12];
  const float* wf1  = (const float*)d_in[13];
  const float* bf1  = (const float*)d_in[14];
  const float* wf2  = (const float*)d_in[15];
  const float* bf2  = (const float*)d_in[16];
  const float* g2   = (const float*)d_in[17];
  const float* b2   = (const float*)d_in[18];
  const float* g3   = (const float*)d_in[19];
  const float* b3   = (const float*)d_in[20];
  float* out = (float*)d_out;

  const size_t MB1 = 1048576;
  char* g = (char*)d_ws;
  __hip_bfloat16* wbf_in  = (__hip_bfloat16*)(g);              // 512 KB
  __hip_bfloat16* wbf_out = (__hip_bfloat16*)(g + 524288);     // 256 KB
  __hip_bfloat16* wbf_f1  = (__hip_bfloat16*)(g + 786432);     // 256 KB
  __hip_bfloat16* wbf_f2  = (__hip_bfloat16*)(g + 1048576);    // 256 KB
  __hip_bfloat16* wbf_xp  = (__hip_bfloat16*)(g + 1310720);    // 128 KB
  const size_t SHARED = 1572864;

  // Regions/batch: RA 4MB (xz|t2b) | RB 1MB (xbf|dlsum) | RC 2MB (y|ffny)
  //   RD 384KB (xdbl) | RE 2MB (hp bf16 | resb+h1bf) | RF 2MB (deltab)
  const size_t PB = 11 * MB1 + 393216;  // 11,927,552 B/batch
  int nb = (int)((ws_size - SHARED) / PB);
  if (ws_size <= SHARED || nb < 1) return;
  if (nb > NBTOT) nb = NBTOT;

  dim3 blk(256);
  cast_bf16_k<<<dim3(256), blk, 0, stream>>>(w_in, wbf_in, 65536);
  cast_bf16_k<<<dim3(128), blk, 0, stream>>>(wout, wbf_out, 32768);
  cast_bf16_k<<<dim3(128), blk, 0, stream>>>(wf1, wbf_f1, 32768);
  cast_bf16_k<<<dim3(128), blk, 0, stream>>>(wf2, wbf_f2, 32768);
  pad_wx_k<<<dim3(64), blk, 0, stream>>>(wx, wbf_xp);

  for (int b0 = 0; b0 < NBTOT; b0 += nb) {
    int bn = (NBTOT - b0 < nb) ? (NBTOT - b0) : nb;
    char* base = g + SHARED;
    char* RA = base;                          // bn*4MB
    char* RB = base + (size_t)bn * 4 * MB1;   // bn*1MB
    char* RC = base + (size_t)bn * 5 * MB1;   // bn*2MB
    char* RD = base + (size_t)bn * 7 * MB1;   // bn*384KB
    char* RE = RD + (size_t)bn * 393216;      // bn*2MB
    char* RF = RE + (size_t)bn * 2 * MB1;     // bn*2MB

    __hip_bfloat16* xz     = (__hip_bfloat16*)RA;
    __hip_bfloat16* t2b    = (__hip_bfloat16*)RA;
    __hip_bfloat16* xbf    = (__hip_bfloat16*)RB;
    float*          dlsum  = (float*)RB;
    __hip_bfloat16* ybf    = (__hip_bfloat16*)RC;
    __hip_bfloat16* ffnybf = (__hip_bfloat16*)RC;
    float*          xdbl   = (float*)RD;
    __hip_bfloat16* hp     = (__hip_bfloat16*)RE;   // Hc in-place (bf16)
    __hip_bfloat16* resb   = (__hip_bfloat16*)RE;   // after scan
    __hip_bfloat16* h1bf   = (__hip_bfloat16*)(RE + (size_t)bn * MB1);
    __hip_bfloat16* deltab = (__hip_bfloat16*)RF;

    const float* xg = x + (size_t)b0 * SEQ * 256;
    float* outg = out + (size_t)b0 * SEQ * 256;
    int M = bn * SEQ;
    int MT = M / 128;

    cast_bf16_k<<<dim3(M * 64 / 256), blk, 0, stream>>>(xg, xbf, M * 64);
    // in_proj (N=1024, NT=8) -> xz bf16
    gemm_bf16<true, false, false, false, true, 3>
        <<<dim3(8 * MT), blk, 0, stream>>>(xbf, wbf_in, b_in, nullptr, nullptr,
                                           xz, 1024, 256);
    // x_proj with fused conv+silu A-staging -> xdbl f32
    gemm_xproj<<<dim3(MT), blk, 0, stream>>>(xz, wbf_xp, cw, cb, xdbl);
    scan_p1<<<dim3(bn * 128), blk, 0, stream>>>(xz, xdbl, alog, wdt, bdt,
                                                cw, cb, dlsum, hp, deltab);
    scan_p2<<<dim3(bn * 32), blk, 0, stream>>>(hp, dlsum, alog);
    scan_p3<<<dim3(bn * 128), blk, 0, stream>>>(alog, deltab, xdbl, hp, Dp,
                                                xz, cw, cb, ybf);
    // out_proj + residual(x f32) -> resb bf16 (N=256, NT=2)
    gemm_bf16<false, false, true, false, true, 1>
        <<<dim3(2 * MT), blk, 0, stream>>>(ybf, wbf_out, nullptr, xg, nullptr,
                                           resb, 256, 512);
    ln_k<<<dim3(M / 4), blk, 0, stream>>>(resb, g1, b1, h1bf);
    // ffn1 + relu (N=512, NT=4) -> ffnybf
    gemm_bf16<true, true, false, false, true, 2>
        <<<dim3(4 * MT), blk, 0, stream>>>(h1bf, wbf_f1, bf1, nullptr, nullptr,
                                           ffnybf, 512, 256);
    // ffn2 + bias + residual(h1 bf16) -> t2b bf16 (N=256, NT=2)
    gemm_bf16<true, false, false, true, true, 1>
        <<<dim3(2 * MT), blk, 0, stream>>>(ffnybf, wbf_f2, bf2, nullptr, h1bf,
                                           t2b, 256, 512);
    final_k<<<dim3(bn * 64), blk, 0, stream>>>(t2b, g2, b2, g3, b3, xg, outg);
  }
}

// Round 13
// 261.745 us; speedup vs baseline: 1.1363x; 1.1363x over previous
//
#include <hip/hip_runtime.h>
#include <hip/hip_bf16.h>
#include <math.h>

#define SEQ    2048
#define NBTOT  16
#define NCH    64
#define CHL    32            // NCH*CHL == SEQ

#define L2E 1.4426950408889634f

typedef __attribute__((ext_vector_type(8))) __bf16 bf16x8;
typedef __attribute__((ext_vector_type(4))) float f32x4;
typedef __attribute__((ext_vector_type(2))) float f32x2;

#define GLOAD16(gp, lp)                                                   \
  __builtin_amdgcn_global_load_lds(                                       \
      (const __attribute__((address_space(1))) unsigned int*)(gp),        \
      (__attribute__((address_space(3))) unsigned int*)(lp), 16, 0, 0)

__device__ __forceinline__ float exp2_(float x) {
  return __builtin_amdgcn_exp2f(x);
}
__device__ __forceinline__ float silu_(float x) {
  return x * __builtin_amdgcn_rcpf(1.f + exp2_(-x * L2E));
}
__device__ __forceinline__ float softplus_(float x) {
  return fmaxf(x, 0.f) + __logf(1.f + exp2_(-fabsf(x) * L2E));
}
__device__ __forceinline__ float wsum_(float v) {
#pragma unroll
  for (int off = 32; off > 0; off >>= 1) v += __shfl_xor(v, off, 64);
  return v;
}
// Bijective XCD-chunk swizzle (nwg mult of 8) — pipeline-consistent row->XCD.
__device__ __forceinline__ int xcdswz_(int bid, int nwg) {
  return (bid & 7) * (nwg >> 3) + (bid >> 3);
}
// p[k] = {e1^(2k+1), e1^(2k+2)}: 2 squares + 7 pk_mul, depth 4
__device__ __forceinline__ void powpairs_(float e1, f32x2 p[8]) {
  float e2 = e1 * e1;
  f32x2 p0; p0.x = e1; p0.y = e2;
  f32x2 s2; s2.x = e2; s2.y = e2;
  f32x2 s4 = s2 * s2;
  f32x2 s8 = s4 * s4;
  p[0] = p0;      p[1] = p0 * s2; p[2] = p0 * s4; p[3] = p[1] * s4;
  p[4] = p0 * s8; p[5] = p[1] * s8; p[6] = p[2] * s8; p[7] = p[3] * s8;
}

// ---------------------------------------------------------------------------
// bf16 MFMA GEMM (m97 structure) + XCD-chunk swizzle + LDS-bounce epilogue.
// ---------------------------------------------------------------------------
template <bool BIAS, bool RELU, bool RES, bool RESB, bool F32OUT, bool BF16OUT,
          int NTLOG>
__global__ __launch_bounds__(256) void gemm_bf16(
    const __hip_bfloat16* __restrict__ A, const __hip_bfloat16* __restrict__ W,
    const float* __restrict__ bias, const float* __restrict__ res,
    const __hip_bfloat16* __restrict__ resb, float* __restrict__ C,
    __hip_bfloat16* __restrict__ Cb, int N, int K) {
  __shared__ __align__(16) char ShRaw[36864];
  short* Als = reinterpret_cast<short*>(ShRaw);
  short* Bls = Als + 8192;
  const int tid = threadIdx.x;
  const int lane = tid & 63;
  const int wid = tid >> 6;
  const int swz = xcdswz_(blockIdx.x, gridDim.x);
  const int m0 = (swz >> NTLOG) * 128;
  const int n0 = (swz & ((1 << NTLOG) - 1)) * 128;
  const int wm = (wid >> 1) * 64;
  const int wn = (wid & 1) * 64;
  const int lr = lane & 15;
  const int lk = lane >> 4;  // 0..3

  f32x4 acc[4][4];
#pragma unroll
  for (int m = 0; m < 4; ++m)
#pragma unroll
    for (int n = 0; n < 4; ++n) acc[m][n] = (f32x4){0.f, 0.f, 0.f, 0.f};

  const int srow = wid * 32 + (lane >> 3);
  const int scol = (lane & 7) * 8;
  const __hip_bfloat16* Ag = A + (size_t)(m0 + srow) * K + scol;
  const __hip_bfloat16* Wg = W + (size_t)(n0 + srow) * K + scol;
  short* Alb = Als + wid * 2048;
  short* Blb = Bls + wid * 2048;

  for (int kt = 0; kt < K; kt += 64) {
#pragma unroll
    for (int i = 0; i < 4; ++i) {
      GLOAD16(Ag + (size_t)(i * 8) * K + kt, Alb + i * 512);
      GLOAD16(Wg + (size_t)(i * 8) * K + kt, Blb + i * 512);
    }
    __syncthreads();
    const bf16x8* Af = reinterpret_cast<const bf16x8*>(Als);
    const bf16x8* Bf = reinterpret_cast<const bf16x8*>(Bls);
#pragma unroll
    for (int ks = 0; ks < 2; ++ks) {
      bf16x8 av[4], bv[4];
#pragma unroll
      for (int m = 0; m < 4; ++m)
        av[m] = Af[(wm + m * 16 + lr) * 8 + ks * 4 + lk];
#pragma unroll
      for (int n = 0; n < 4; ++n)
        bv[n] = Bf[(wn + n * 16 + lr) * 8 + ks * 4 + lk];
#pragma unroll
      for (int m = 0; m < 4; ++m)
#pragma unroll
        for (int n = 0; n < 4; ++n)
          acc[m][n] = __builtin_amdgcn_mfma_f32_16x16x32_bf16(
              av[m], bv[n], acc[m][n], 0, 0, 0);
    }
    __syncthreads();  // staging LDS dead after -> epilogue reuse
  }

  if (BF16OUT) {
    __hip_bfloat16* epi =
        reinterpret_cast<__hip_bfloat16*>(ShRaw) + wid * 4608;
#pragma unroll
    for (int n = 0; n < 4; ++n) {
      int col = n0 + wn + n * 16 + lr;
      float bval = BIAS ? bias[col] : 0.f;
#pragma unroll
      for (int m = 0; m < 4; ++m) {
        int lrow = m * 16 + lk * 4;
#pragma unroll
        for (int r = 0; r < 4; ++r) {
          float v = acc[m][n][r];
          if (BIAS) v += bval;
          if (RES) v += res[(size_t)(m0 + wm + lrow + r) * N + col];
          if (RESB)
            v += __bfloat162float(resb[(size_t)(m0 + wm + lrow + r) * N + col]);
          if (RELU) v = fmaxf(v, 0.f);
          epi[(lrow + r) * 72 + n * 16 + lr] = __float2bfloat16(v);
        }
      }
    }
    const int lr8 = (lane & 7) * 8;
    const int lrw = lane >> 3;
    const size_t obase = (size_t)(m0 + wm) * N + n0 + wn + lr8;
#pragma unroll
    for (int j = 0; j < 8; ++j) {
      int row = j * 8 + lrw;
      int4 vv = *reinterpret_cast<const int4*>(epi + row * 72 + lr8);
      *reinterpret_cast<int4*>(&Cb[obase + (size_t)row * N]) = vv;
    }
  }
  if (F32OUT) {
#pragma unroll
    for (int n = 0; n < 4; ++n) {
      int col = n0 + wn + n * 16 + lr;
      if (col >= N) continue;
      float bval = BIAS ? bias[col] : 0.f;
#pragma unroll
      for (int m = 0; m < 4; ++m) {
        int row0 = m0 + wm + m * 16 + lk * 4;
#pragma unroll
        for (int r = 0; r < 4; ++r) {
          size_t off = (size_t)(row0 + r) * N + col;
          float v = acc[m][n][r];
          if (BIAS) v += bval;
          if (RES) v += res[off];
          if (RESB) v += __bfloat162float(resb[off]);
          if (RELU) v = fmaxf(v, 0.f);
          C[off] = v;
        }
      }
    }
  }
}

// ---------------------------------------------------------------------------
__global__ __launch_bounds__(256) void cast_bf16_k(
    const float* __restrict__ src, __hip_bfloat16* __restrict__ dst, int n4) {
  int i = xcdswz_(blockIdx.x, gridDim.x) * 256 + threadIdx.x;
  if (i >= n4) return;
  float4 v = reinterpret_cast<const float4*>(src)[i];
  union { __hip_bfloat16 h[4]; short4 s4; } u;
  u.h[0] = __float2bfloat16(v.x); u.h[1] = __float2bfloat16(v.y);
  u.h[2] = __float2bfloat16(v.z); u.h[3] = __float2bfloat16(v.w);
  reinterpret_cast<short4*>(dst)[i] = u.s4;
}

__global__ __launch_bounds__(256) void pad_wx_k(
    const float* __restrict__ src, __hip_bfloat16* __restrict__ dst) {
  int i = blockIdx.x * 256 + threadIdx.x;
  int row = i >> 7;
  union { __hip_bfloat16 h[4]; short4 s4; } u;
  if (row < 48) {
    float4 v = reinterpret_cast<const float4*>(src)[i];
    u.h[0] = __float2bfloat16(v.x); u.h[1] = __float2bfloat16(v.y);
    u.h[2] = __float2bfloat16(v.z); u.h[3] = __float2bfloat16(v.w);
  } else {
    u.h[0] = u.h[1] = u.h[2] = u.h[3] = __float2bfloat16(0.f);
  }
  reinterpret_cast<short4*>(dst)[i] = u.s4;
}

// ---------------------------------------------------------------------------
// Depthwise causal conv (D_CONV=4) + SiLU, 2 rows/thread (windows overlap:
// 5 int4 loads produce 2 output rows). In: xz (rows,1024) cols 0..511.
// Row pairs (2rp, 2rp+1) never straddle a batch boundary (SEQ even).
// ---------------------------------------------------------------------------
__global__ __launch_bounds__(256) void conv_silu_k(
    const __hip_bfloat16* __restrict__ xz, const float* __restrict__ cw,
    const float* __restrict__ cb, __hip_bfloat16* __restrict__ xi) {
  int idx = xcdswz_(blockIdx.x, gridDim.x) * 256 + threadIdx.x;  // rp*64 + t
  int t = idx & 63;
  int rp = idx >> 6;
  int r = rp << 1;
  int l = r & (SEQ - 1);   // even; l+1 stays in-batch
  int c8 = t << 3;
  const __hip_bfloat16* p = xz + (size_t)r * 1024 + c8;
  union U8 { int4 v; __hip_bfloat16 h[8]; } x0, x1, x2, x3, x4, oa, ob;
  const int4 z4 = make_int4(0, 0, 0, 0);
  x4.v = *reinterpret_cast<const int4*>(p + 1024);
  x3.v = *reinterpret_cast<const int4*>(p);
  x2.v = (l >= 1) ? *reinterpret_cast<const int4*>(p - 1024) : z4;
  x1.v = (l >= 2) ? *reinterpret_cast<const int4*>(p - 2048) : z4;
  x0.v = (l >= 3) ? *reinterpret_cast<const int4*>(p - 3072) : z4;
  const float4* cw4 = reinterpret_cast<const float4*>(cw);
#pragma unroll
  for (int j = 0; j < 8; ++j) {
    float4 w = cw4[c8 + j];
    float b = cb[c8 + j];
    float f0 = __bfloat162float(x0.h[j]);
    float f1 = __bfloat162float(x1.h[j]);
    float f2 = __bfloat162float(x2.h[j]);
    float f3 = __bfloat162float(x3.h[j]);
    float f4 = __bfloat162float(x4.h[j]);
    float a0 = fmaf(w.w, f3, fmaf(w.z, f2, fmaf(w.y, f1, fmaf(w.x, f0, b))));
    float a1 = fmaf(w.w, f4, fmaf(w.z, f3, fmaf(w.y, f2, fmaf(w.x, f1, b))));
    oa.h[j] = __float2bfloat16(silu_(a0));
    ob.h[j] = __float2bfloat16(silu_(a1));
  }
  *reinterpret_cast<int4*>(&xi[(size_t)r * 512 + c8]) = oa.v;
  *reinterpret_cast<int4*>(&xi[(size_t)(r + 1) * 512 + c8]) = ob.v;
}

// ---------------------------------------------------------------------------
// Chunked selective scan (R11 form: reads xi; deltab bf16; hp bf16; dlsum).
// ---------------------------------------------------------------------------
__global__ __launch_bounds__(256) void scan_p1(
    const __hip_bfloat16* __restrict__ u, const float* __restrict__ xdbl,
    const float* __restrict__ A_log, const float* __restrict__ wdt,
    const float* __restrict__ bdt, float* __restrict__ dlsum,
    __hip_bfloat16* __restrict__ hp, __hip_bfloat16* __restrict__ deltab) {
  const int w = xcdswz_(blockIdx.x, gridDim.x);  // b*128 + c*2 + h
  const int b = w >> 7;
  const int c = (w >> 1) & 63;
  const int d = ((w & 1) << 8) + threadIdx.x;
  const int l0 = c * CHL;
  float A2[16];
  f32x2 w2[8];
  {
    const float4* aq = reinterpret_cast<const float4*>(&A_log[d * 16]);
    const f32x2* wq = reinterpret_cast<const f32x2*>(&wdt[d * 16]);
#pragma unroll
    for (int q = 0; q < 4; ++q) {
      float4 v = aq[q];
      A2[q * 4 + 0] = -exp2_(v.x * L2E) * L2E;
      A2[q * 4 + 1] = -exp2_(v.y * L2E) * L2E;
      A2[q * 4 + 2] = -exp2_(v.z * L2E) * L2E;
      A2[q * 4 + 3] = -exp2_(v.w * L2E) * L2E;
    }
#pragma unroll
    for (int k = 0; k < 8; ++k) w2[k] = wq[k];
  }
  bool chainok = true;
#pragma unroll
  for (int n = 1; n < 16; ++n)
    chainok = chainok &&
              (fabsf(A2[n] - (float)(n + 1) * A2[0]) <=
               1e-4f * (float)(n + 1) * fabsf(A2[0]));
  const float bdtd = bdt[d];
  const float nL = A2[0];
  f32x2 h2[8];
#pragma unroll
  for (int k = 0; k < 8; ++k) h2[k] = (f32x2){0.f, 0.f};
  float dls = 0.f;
  size_t base = (size_t)(b * SEQ + l0) * 512 + d;
  const float* rowp = xdbl + (size_t)(b * SEQ + l0) * 48;
  if (chainok) {
#pragma unroll 4
    for (int i = 0; i < CHL; ++i) {
      const f32x2* r2 = reinterpret_cast<const f32x2*>(rowp + i * 48);
      f32x2 acc2; acc2.x = bdtd; acc2.y = 0.f;
#pragma unroll
      for (int k = 0; k < 8; ++k)
        acc2 = __builtin_elementwise_fma(r2[k], w2[k], acc2);
      float dl = softplus_(acc2.x + acc2.y);
      deltab[base + (size_t)i * 512] = __float2bfloat16(dl);
      dls += dl;
      float du = dl * __bfloat162float(u[base + (size_t)i * 512]);
      f32x2 p[8];
      powpairs_(exp2_(dl * nL), p);
      f32x2 du2; du2.x = du; du2.y = du;
#pragma unroll
      for (int k = 0; k < 8; ++k)
        h2[k] = __builtin_elementwise_fma(p[k], h2[k], du2 * r2[8 + k]);
    }
  } else {
#pragma unroll 2
    for (int i = 0; i < CHL; ++i) {
      const f32x2* r2 = reinterpret_cast<const f32x2*>(rowp + i * 48);
      f32x2 acc2; acc2.x = bdtd; acc2.y = 0.f;
#pragma unroll
      for (int k = 0; k < 8; ++k)
        acc2 = __builtin_elementwise_fma(r2[k], w2[k], acc2);
      float dl = softplus_(acc2.x + acc2.y);
      deltab[base + (size_t)i * 512] = __float2bfloat16(dl);
      dls += dl;
      float du = dl * __bfloat162float(u[base + (size_t)i * 512]);
      f32x2 du2; du2.x = du; du2.y = du;
#pragma unroll
      for (int k = 0; k < 8; ++k) {
        f32x2 a; a.x = exp2_(dl * A2[2 * k]); a.y = exp2_(dl * A2[2 * k + 1]);
        h2[k] = __builtin_elementwise_fma(a, h2[k], du2 * r2[8 + k]);
      }
    }
  }
  size_t sc = (size_t)(b * NCH + c) * 512 + d;
  dlsum[sc] = dls;
  union { __hip_bfloat16 h[4]; short4 s4; } o0, o1, o2, o3;
#pragma unroll
  for (int j = 0; j < 2; ++j) {
    o0.h[2*j] = __float2bfloat16(h2[j].x);   o0.h[2*j+1] = __float2bfloat16(h2[j].y);
    o1.h[2*j] = __float2bfloat16(h2[2+j].x); o1.h[2*j+1] = __float2bfloat16(h2[2+j].y);
    o2.h[2*j] = __float2bfloat16(h2[4+j].x); o2.h[2*j+1] = __float2bfloat16(h2[4+j].y);
    o3.h[2*j] = __float2bfloat16(h2[6+j].x); o3.h[2*j+1] = __float2bfloat16(h2[6+j].y);
  }
  short4* hq = reinterpret_cast<short4*>(hp + sc * 16);
  hq[0] = o0.s4; hq[1] = o1.s4; hq[2] = o2.s4; hq[3] = o3.s4;
}

// In-place: Hc overwrites hp (in-thread read-before-write per idx).
__global__ __launch_bounds__(256) void scan_p2(
    __hip_bfloat16* hp, const float* __restrict__ dlsum,
    const float* __restrict__ A_log) {
  int g = xcdswz_(blockIdx.x, gridDim.x) * 256 + threadIdx.x;
  int b = g >> 13;
  int dn = g & 8191;
  int d = dn >> 4;
  float A2n = -exp2_(A_log[dn] * L2E) * L2E;
  float H = 0.f;
  for (int c = 0; c < NCH; ++c) {
    float ds = dlsum[(size_t)(b * NCH + c) * 512 + d];
    size_t idx = (size_t)(b * NCH + c) * 8192 + dn;
    float p = __bfloat162float(hp[idx]);
    float a = exp2_(A2n * ds);
    hp[idx] = __float2bfloat16(H);
    H = fmaf(a, H, p);
  }
}

__global__ __launch_bounds__(256) void scan_p3(
    const __hip_bfloat16* u,  // aliases y (same-thread read-before-write)
    const float* __restrict__ A_log,
    const __hip_bfloat16* __restrict__ deltab, const float* __restrict__ xdbl,
    const __hip_bfloat16* __restrict__ Hc, const float* __restrict__ Dp,
    const __hip_bfloat16* __restrict__ xz, __hip_bfloat16* y) {
  const int w = xcdswz_(blockIdx.x, gridDim.x);
  const int b = w >> 7;
  const int c = (w >> 1) & 63;
  const int d = ((w & 1) << 8) + threadIdx.x;
  const int l0 = c * CHL;
  float A2[16];
  {
    const float4* aq = reinterpret_cast<const float4*>(&A_log[d * 16]);
#pragma unroll
    for (int q = 0; q < 4; ++q) {
      float4 v = aq[q];
      A2[q * 4 + 0] = -exp2_(v.x * L2E) * L2E;
      A2[q * 4 + 1] = -exp2_(v.y * L2E) * L2E;
      A2[q * 4 + 2] = -exp2_(v.z * L2E) * L2E;
      A2[q * 4 + 3] = -exp2_(v.w * L2E) * L2E;
    }
  }
  bool chainok = true;
#pragma unroll
  for (int n = 1; n < 16; ++n)
    chainok = chainok &&
              (fabsf(A2[n] - (float)(n + 1) * A2[0]) <=
               1e-4f * (float)(n + 1) * fabsf(A2[0]));
  const float nL = A2[0];
  f32x2 h2[8];
  {
    const short4* hq =
        reinterpret_cast<const short4*>(Hc + ((size_t)(b * NCH + c) * 512 + d) * 16);
#pragma unroll
    for (int q = 0; q < 4; ++q) {
      union { short4 s4; __hip_bfloat16 h[4]; } iv;
      iv.s4 = hq[q];
      h2[2*q].x = __bfloat162float(iv.h[0]);
      h2[2*q].y = __bfloat162float(iv.h[1]);
      h2[2*q+1].x = __bfloat162float(iv.h[2]);
      h2[2*q+1].y = __bfloat162float(iv.h[3]);
    }
  }
  const float Dpd = Dp[d];
  size_t base = (size_t)(b * SEQ + l0) * 512 + d;
  const float* rowp = xdbl + (size_t)(b * SEQ + l0) * 48;
  const __hip_bfloat16* zp = xz + (size_t)(b * SEQ + l0) * 1024 + 512 + d;
  if (chainok) {
#pragma unroll 4
    for (int i = 0; i < CHL; ++i) {
      const f32x2* r2 = reinterpret_cast<const f32x2*>(rowp + i * 48);
      float dl = __bfloat162float(deltab[base + (size_t)i * 512]);
      float ul = __bfloat162float(u[base + (size_t)i * 512]);
      float du = dl * ul;
      f32x2 p[8];
      powpairs_(exp2_(dl * nL), p);
      f32x2 du2; du2.x = du; du2.y = du;
      f32x2 yv2; yv2.x = 0.f; yv2.y = 0.f;
#pragma unroll
      for (int k = 0; k < 8; ++k) {
        h2[k] = __builtin_elementwise_fma(p[k], h2[k], du2 * r2[8 + k]);
        yv2 = __builtin_elementwise_fma(h2[k], r2[16 + k], yv2);
      }
      float yv = yv2.x + yv2.y;
      float zv = __bfloat162float(zp[(size_t)i * 1024]);
      y[base + (size_t)i * 512] =
          __float2bfloat16((yv + ul * Dpd) * silu_(zv));
    }
  } else {
#pragma unroll 2
    for (int i = 0; i < CHL; ++i) {
      const f32x2* r2 = reinterpret_cast<const f32x2*>(rowp + i * 48);
      float dl = __bfloat162float(deltab[base + (size_t)i * 512]);
      float ul = __bfloat162float(u[base + (size_t)i * 512]);
      float du = dl * ul;
      f32x2 du2; du2.x = du; du2.y = du;
      f32x2 yv2; yv2.x = 0.f; yv2.y = 0.f;
#pragma unroll
      for (int k = 0; k < 8; ++k) {
        f32x2 a; a.x = exp2_(dl * A2[2 * k]); a.y = exp2_(dl * A2[2 * k + 1]);
        h2[k] = __builtin_elementwise_fma(a, h2[k], du2 * r2[8 + k]);
        yv2 = __builtin_elementwise_fma(h2[k], r2[16 + k], yv2);
      }
      float yv = yv2.x + yv2.y;
      float zv = __bfloat162float(zp[(size_t)i * 1024]);
      y[base + (size_t)i * 512] =
          __float2bfloat16((yv + ul * Dpd) * silu_(zv));
    }
  }
}

// ---------------------------------------------------------------------------
__global__ __launch_bounds__(256) void ln_k(
    const __hip_bfloat16* __restrict__ in, const float* __restrict__ g,
    const float* __restrict__ bb, __hip_bfloat16* __restrict__ outb) {
  int row = (xcdswz_(blockIdx.x, gridDim.x) * 256 + threadIdx.x) >> 6;
  int lane = threadIdx.x & 63;
  union { short4 s4; __hip_bfloat16 h[4]; } iv;
  iv.s4 = reinterpret_cast<const short4*>(in)[row * 64 + lane];
  float v0 = __bfloat162float(iv.h[0]), v1 = __bfloat162float(iv.h[1]);
  float v2 = __bfloat162float(iv.h[2]), v3 = __bfloat162float(iv.h[3]);
  float mu = wsum_(v0 + v1 + v2 + v3) * (1.f / 256.f);
  float a0 = v0 - mu, a1 = v1 - mu, a2 = v2 - mu, a3 = v3 - mu;
  float var = wsum_(a0 * a0 + a1 * a1 + a2 * a2 + a3 * a3) * (1.f / 256.f);
  float rs = __builtin_amdgcn_rsqf(var + 1e-5f);
  float4 gg = *reinterpret_cast<const float4*>(&g[lane * 4]);
  float4 bq = *reinterpret_cast<const float4*>(&bb[lane * 4]);
  union { __hip_bfloat16 h[4]; short4 s4; } u;
  u.h[0] = __float2bfloat16(a0 * rs * gg.x + bq.x);
  u.h[1] = __float2bfloat16(a1 * rs * gg.y + bq.y);
  u.h[2] = __float2bfloat16(a2 * rs * gg.z + bq.z);
  u.h[3] = __float2bfloat16(a3 * rs * gg.w + bq.w);
  reinterpret_cast<short4*>(outb)[row * 64 + lane] = u.s4;
}

// ---------------------------------------------------------------------------
__global__ __launch_bounds__(256) void final_k(
    const __hip_bfloat16* __restrict__ t2, const float* __restrict__ g2v,
    const float* __restrict__ b2v, const float* __restrict__ g3v,
    const float* __restrict__ b3v, const float* __restrict__ x,
    float* __restrict__ out) {
  int bx = xcdswz_(blockIdx.x, gridDim.x);
  int half = bx & 1, nv = (bx >> 1) & 31, b = bx >> 6;
  int wave = threadIdx.x >> 6, lane = threadIdx.x & 63;
  __shared__ float sh[32][257];
  float4 gg2 = *reinterpret_cast<const float4*>(&g2v[lane * 4]);
  float4 bb2 = *reinterpret_cast<const float4*>(&b2v[lane * 4]);
  float4 gg3 = *reinterpret_cast<const float4*>(&g3v[lane * 4]);
  float4 bb3 = *reinterpret_cast<const float4*>(&b3v[lane * 4]);
#pragma unroll
  for (int i = 0; i < 8; ++i) {
    int pn = wave * 8 + i;
    int r = ((b * 32 + nv) << 6) + (half << 5) + pn;
    union { short4 s4; __hip_bfloat16 h[4]; } iv;
    iv.s4 = reinterpret_cast<const short4*>(t2)[r * 64 + lane];
    float v0 = __bfloat162float(iv.h[0]), v1 = __bfloat162float(iv.h[1]);
    float v2 = __bfloat162float(iv.h[2]), v3 = __bfloat162float(iv.h[3]);
    float mu = wsum_(v0 + v1 + v2 + v3) * (1.f / 256.f);
    float a0 = v0 - mu, a1 = v1 - mu, a2 = v2 - mu, a3 = v3 - mu;
    float var = wsum_(a0 * a0 + a1 * a1 + a2 * a2 + a3 * a3) * (1.f / 256.f);
    float rs = __builtin_amdgcn_rsqf(var + 1e-5f);
    a0 = a0 * rs * gg2.x + bb2.x; a1 = a1 * rs * gg2.y + bb2.y;
    a2 = a2 * rs * gg2.z + bb2.z; a3 = a3 * rs * gg2.w + bb2.w;
    mu = wsum_(a0 + a1 + a2 + a3) * (1.f / 256.f);
    float c0 = a0 - mu, c1 = a1 - mu, c2 = a2 - mu, c3 = a3 - mu;
    var = wsum_(c0 * c0 + c1 * c1 + c2 * c2 + c3 * c3) * (1.f / 256.f);
    rs = __builtin_amdgcn_rsqf(var + 1e-5f);
    sh[pn][lane * 4 + 0] = c0 * rs * gg3.x + bb3.x;
    sh[pn][lane * 4 + 1] = c1 * rs * gg3.y + bb3.y;
    sh[pn][lane * 4 + 2] = c2 * rs * gg3.z + bb3.z;
    sh[pn][lane * 4 + 3] = c3 * rs * gg3.w + bb3.w;
  }
  __syncthreads();
  int pnl = threadIdx.x & 31;
  int dbase = threadIdx.x >> 5;
  size_t obase = (size_t)((b * 32 + nv) * 256) * 64 + (half << 5) + pnl;
#pragma unroll
  for (int k = 0; k < 32; ++k) {
    int dd = dbase + (k << 3);
    size_t oi = obase + (size_t)dd * 64;
    out[oi] = sh[pnl][dd] + x[oi];
  }
}

// ---------------------------------------------------------------------------
extern "C" void kernel_launch(void* const* d_in, const int* in_sizes, int n_in,
                              void* d_out, int out_size, void* d_ws,
                              size_t ws_size, hipStream_t stream) {
  const float* x    = (const float*)d_in[0];
  const float* w_in = (const float*)d_in[1];
  const float* b_in = (const float*)d_in[2];
  const float* cw   = (const float*)d_in[3];
  const float* cb   = (const float*)d_in[4];
  const float* wx   = (const float*)d_in[5];
  const float* wdt  = (const float*)d_in[6];
  const float* bdt  = (const float*)d_in[7];
  const float* alog = (const float*)d_in[8];
  const float* Dp   = (const float*)d_in[9];
  const float* wout = (const float*)d_in[10];
  const float* g1   = (const float*)d_in[11];
  const float* b1   = (const float*)d_in[12];
  const float* wf1  = (const float*)d_in[13];
  const float* bf1  = (const float*)d_in[14];
  const float* wf2  = (const float*)d_in[15];
  const float* bf2  = (const float*)d_in[16];
  const float* g2   = (const float*)d_in[17];
  const float* b2   = (const float*)d_in[18];
  const float* g3   = (const float*)d_in[19];
  const float* b3   = (const float*)d_in[20];
  float* out = (float*)d_out;

  const size_t MB1 = 1048576;
  char* g = (char*)d_ws;
  __hip_bfloat16* wbf_in  = (__hip_bfloat16*)(g);              // 512 KB
  __hip_bfloat16* wbf_out = (__hip_bfloat16*)(g + 524288);     // 256 KB
  __hip_bfloat16* wbf_f1  = (__hip_bfloat16*)(g + 786432);     // 256 KB
  __hip_bfloat16* wbf_f2  = (__hip_bfloat16*)(g + 1048576);    // 256 KB
  __hip_bfloat16* wbf_xp  = (__hip_bfloat16*)(g + 1310720);    // 128 KB
  const size_t SHARED = 1572864;

  // Regions/batch: RA 4MB (xz|t2b) | RB 1MB (xbf|dlsum) | RC 2MB (xi|ffny)
  //   RD 384KB (xdbl) | RE 2MB (hp bf16 | resb+h1bf) | RF 2MB (deltab)
  const size_t PB = 11 * MB1 + 393216;  // 11,927,552 B/batch
  int nb = (int)((ws_size - SHARED) / PB);
  if (ws_size <= SHARED || nb < 1) return;
  if (nb > NBTOT) nb = NBTOT;

  dim3 blk(256);
  cast_bf16_k<<<dim3(256), blk, 0, stream>>>(w_in, wbf_in, 65536);
  cast_bf16_k<<<dim3(128), blk, 0, stream>>>(wout, wbf_out, 32768);
  cast_bf16_k<<<dim3(128), blk, 0, stream>>>(wf1, wbf_f1, 32768);
  cast_bf16_k<<<dim3(128), blk, 0, stream>>>(wf2, wbf_f2, 32768);
  pad_wx_k<<<dim3(64), blk, 0, stream>>>(wx, wbf_xp);

  for (int b0 = 0; b0 < NBTOT; b0 += nb) {
    int bn = (NBTOT - b0 < nb) ? (NBTOT - b0) : nb;
    char* base = g + SHARED;
    char* RA = base;                          // bn*4MB
    char* RB = base + (size_t)bn * 4 * MB1;   // bn*1MB
    char* RC = base + (size_t)bn * 5 * MB1;   // bn*2MB
    char* RD = base + (size_t)bn * 7 * MB1;   // bn*384KB
    char* RE = RD + (size_t)bn * 393216;      // bn*2MB
    char* RF = RE + (size_t)bn * 2 * MB1;     // bn*2MB

    __hip_bfloat16* xz     = (__hip_bfloat16*)RA;
    __hip_bfloat16* t2b    = (__hip_bfloat16*)RA;
    __hip_bfloat16* xbf    = (__hip_bfloat16*)RB;
    float*          dlsum  = (float*)RB;
    __hip_bfloat16* xibf   = (__hip_bfloat16*)RC;
    __hip_bfloat16* ffnybf = (__hip_bfloat16*)RC;
    float*          xdbl   = (float*)RD;
    __hip_bfloat16* hp     = (__hip_bfloat16*)RE;   // Hc in-place (bf16)
    __hip_bfloat16* resb   = (__hip_bfloat16*)RE;   // after scan
    __hip_bfloat16* h1bf   = (__hip_bfloat16*)(RE + (size_t)bn * MB1);
    __hip_bfloat16* deltab = (__hip_bfloat16*)RF;

    const float* xg = x + (size_t)b0 * SEQ * 256;
    float* outg = out + (size_t)b0 * SEQ * 256;
    int M = bn * SEQ;
    int MT = M / 128;

    cast_bf16_k<<<dim3(M * 64 / 256), blk, 0, stream>>>(xg, xbf, M * 64);
    // in_proj (N=1024, NT=8) -> xz bf16
    gemm_bf16<true, false, false, false, false, true, 3>
        <<<dim3(8 * MT), blk, 0, stream>>>(xbf, wbf_in, b_in, nullptr, nullptr,
                                           nullptr, xz, 1024, 256);
    conv_silu_k<<<dim3(M / 8), blk, 0, stream>>>(xz, cw, cb, xibf);
    // x_proj (N=48 padded, NT=1) -> xdbl f32
    gemm_bf16<false, false, false, false, true, false, 0>
        <<<dim3(MT), blk, 0, stream>>>(xibf, wbf_xp, nullptr, nullptr,
                                       nullptr, xdbl, nullptr, 48, 512);
    scan_p1<<<dim3(bn * 128), blk, 0, stream>>>(xibf, xdbl, alog, wdt, bdt,
                                                dlsum, hp, deltab);
    scan_p2<<<dim3(bn * 32), blk, 0, stream>>>(hp, dlsum, alog);
    scan_p3<<<dim3(bn * 128), blk, 0, stream>>>(xibf, alog, deltab, xdbl,
                                                hp, Dp, xz, xibf);
    // out_proj + residual(x f32) -> resb bf16 (N=256, NT=2)
    gemm_bf16<false, false, true, false, false, true, 1>
        <<<dim3(2 * MT), blk, 0, stream>>>(xibf, wbf_out, nullptr, xg, nullptr,
                                           nullptr, resb, 256, 512);
    ln_k<<<dim3(M / 4), blk, 0, stream>>>(resb, g1, b1, h1bf);
    // ffn1 + relu (N=512, NT=4) -> ffnybf
    gemm_bf16<true, true, false, false, false, true, 2>
        <<<dim3(4 * MT), blk, 0, stream>>>(h1bf, wbf_f1, bf1, nullptr, nullptr,
                                           nullptr, ffnybf, 512, 256);
    // ffn2 + bias + residual(h1 bf16) -> t2b bf16 (N=256, NT=2)
    gemm_bf16<true, false, false, true, false, true, 1>
        <<<dim3(2 * MT), blk, 0, stream>>>(ffnybf, wbf_f2, bf2, nullptr, h1bf,
                                           nullptr, t2b, 256, 512);
    final_k<<<dim3(bn * 64), blk, 0, stream>>>(t2b, g2, b2, g3, b3, xg, outg);
  }
}

// Round 14
// 260.367 us; speedup vs baseline: 1.1424x; 1.0053x over previous
//
#include <hip/hip_runtime.h>
#include <hip/hip_bf16.h>
#include <math.h>

#define SEQ    2048
#define NBTOT  16
#define NCH    64
#define CHL    32            // NCH*CHL == SEQ

#define L2E 1.4426950408889634f

typedef __attribute__((ext_vector_type(8))) __bf16 bf16x8;
typedef __attribute__((ext_vector_type(4))) float f32x4;
typedef __attribute__((ext_vector_type(2))) float f32x2;

#define GLOAD16(gp, lp)                                                   \
  __builtin_amdgcn_global_load_lds(                                       \
      (const __attribute__((address_space(1))) unsigned int*)(gp),        \
      (__attribute__((address_space(3))) unsigned int*)(lp), 16, 0, 0)

__device__ __forceinline__ float exp2_(float x) {
  return __builtin_amdgcn_exp2f(x);
}
__device__ __forceinline__ float silu_(float x) {
  return x * __builtin_amdgcn_rcpf(1.f + exp2_(-x * L2E));
}
__device__ __forceinline__ float softplus_(float x) {
  return fmaxf(x, 0.f) + __logf(1.f + exp2_(-fabsf(x) * L2E));
}
__device__ __forceinline__ float wsum_(float v) {
#pragma unroll
  for (int off = 32; off > 0; off >>= 1) v += __shfl_xor(v, off, 64);
  return v;
}
// Bijective XCD-chunk swizzle (nwg mult of 8) — pipeline-consistent row->XCD.
__device__ __forceinline__ int xcdswz_(int bid, int nwg) {
  return (bid & 7) * (nwg >> 3) + (bid >> 3);
}
// p[k] = {e1^(2k+1), e1^(2k+2)}: 2 squares + 7 pk_mul, depth 4
__device__ __forceinline__ void powpairs_(float e1, f32x2 p[8]) {
  float e2 = e1 * e1;
  f32x2 p0; p0.x = e1; p0.y = e2;
  f32x2 s2; s2.x = e2; s2.y = e2;
  f32x2 s4 = s2 * s2;
  f32x2 s8 = s4 * s4;
  p[0] = p0;      p[1] = p0 * s2; p[2] = p0 * s4; p[3] = p[1] * s4;
  p[4] = p0 * s8; p[5] = p[1] * s8; p[6] = p[2] * s8; p[7] = p[3] * s8;
}

// ---------------------------------------------------------------------------
// bf16 MFMA GEMM (m97 structure) + XCD-chunk swizzle + LDS-bounce epilogue.
// ---------------------------------------------------------------------------
template <bool BIAS, bool RELU, bool RES, bool RESB, bool F32OUT, bool BF16OUT,
          int NTLOG>
__global__ __launch_bounds__(256) void gemm_bf16(
    const __hip_bfloat16* __restrict__ A, const __hip_bfloat16* __restrict__ W,
    const float* __restrict__ bias, const float* __restrict__ res,
    const __hip_bfloat16* __restrict__ resb, float* __restrict__ C,
    __hip_bfloat16* __restrict__ Cb, int N, int K) {
  __shared__ __align__(16) char ShRaw[36864];
  short* Als = reinterpret_cast<short*>(ShRaw);
  short* Bls = Als + 8192;
  const int tid = threadIdx.x;
  const int lane = tid & 63;
  const int wid = tid >> 6;
  const int swz = xcdswz_(blockIdx.x, gridDim.x);
  const int m0 = (swz >> NTLOG) * 128;
  const int n0 = (swz & ((1 << NTLOG) - 1)) * 128;
  const int wm = (wid >> 1) * 64;
  const int wn = (wid & 1) * 64;
  const int lr = lane & 15;
  const int lk = lane >> 4;  // 0..3

  f32x4 acc[4][4];
#pragma unroll
  for (int m = 0; m < 4; ++m)
#pragma unroll
    for (int n = 0; n < 4; ++n) acc[m][n] = (f32x4){0.f, 0.f, 0.f, 0.f};

  const int srow = wid * 32 + (lane >> 3);
  const int scol = (lane & 7) * 8;
  const __hip_bfloat16* Ag = A + (size_t)(m0 + srow) * K + scol;
  const __hip_bfloat16* Wg = W + (size_t)(n0 + srow) * K + scol;
  short* Alb = Als + wid * 2048;
  short* Blb = Bls + wid * 2048;

  for (int kt = 0; kt < K; kt += 64) {
#pragma unroll
    for (int i = 0; i < 4; ++i) {
      GLOAD16(Ag + (size_t)(i * 8) * K + kt, Alb + i * 512);
      GLOAD16(Wg + (size_t)(i * 8) * K + kt, Blb + i * 512);
    }
    __syncthreads();
    const bf16x8* Af = reinterpret_cast<const bf16x8*>(Als);
    const bf16x8* Bf = reinterpret_cast<const bf16x8*>(Bls);
#pragma unroll
    for (int ks = 0; ks < 2; ++ks) {
      bf16x8 av[4], bv[4];
#pragma unroll
      for (int m = 0; m < 4; ++m)
        av[m] = Af[(wm + m * 16 + lr) * 8 + ks * 4 + lk];
#pragma unroll
      for (int n = 0; n < 4; ++n)
        bv[n] = Bf[(wn + n * 16 + lr) * 8 + ks * 4 + lk];
#pragma unroll
      for (int m = 0; m < 4; ++m)
#pragma unroll
        for (int n = 0; n < 4; ++n)
          acc[m][n] = __builtin_amdgcn_mfma_f32_16x16x32_bf16(
              av[m], bv[n], acc[m][n], 0, 0, 0);
    }
    __syncthreads();  // staging LDS dead after -> epilogue reuse
  }

  if (BF16OUT) {
    __hip_bfloat16* epi =
        reinterpret_cast<__hip_bfloat16*>(ShRaw) + wid * 4608;
#pragma unroll
    for (int n = 0; n < 4; ++n) {
      int col = n0 + wn + n * 16 + lr;
      float bval = BIAS ? bias[col] : 0.f;
#pragma unroll
      for (int m = 0; m < 4; ++m) {
        int lrow = m * 16 + lk * 4;
#pragma unroll
        for (int r = 0; r < 4; ++r) {
          float v = acc[m][n][r];
          if (BIAS) v += bval;
          if (RES) v += res[(size_t)(m0 + wm + lrow + r) * N + col];
          if (RESB)
            v += __bfloat162float(resb[(size_t)(m0 + wm + lrow + r) * N + col]);
          if (RELU) v = fmaxf(v, 0.f);
          epi[(lrow + r) * 72 + n * 16 + lr] = __float2bfloat16(v);
        }
      }
    }
    const int lr8 = (lane & 7) * 8;
    const int lrw = lane >> 3;
    const size_t obase = (size_t)(m0 + wm) * N + n0 + wn + lr8;
#pragma unroll
    for (int j = 0; j < 8; ++j) {
      int row = j * 8 + lrw;
      int4 vv = *reinterpret_cast<const int4*>(epi + row * 72 + lr8);
      *reinterpret_cast<int4*>(&Cb[obase + (size_t)row * N]) = vv;
    }
  }
  if (F32OUT) {
#pragma unroll
    for (int n = 0; n < 4; ++n) {
      int col = n0 + wn + n * 16 + lr;
      if (col >= N) continue;
      float bval = BIAS ? bias[col] : 0.f;
#pragma unroll
      for (int m = 0; m < 4; ++m) {
        int row0 = m0 + wm + m * 16 + lk * 4;
#pragma unroll
        for (int r = 0; r < 4; ++r) {
          size_t off = (size_t)(row0 + r) * N + col;
          float v = acc[m][n][r];
          if (BIAS) v += bval;
          if (RES) v += res[off];
          if (RESB) v += __bfloat162float(resb[off]);
          if (RELU) v = fmaxf(v, 0.f);
          C[off] = v;
        }
      }
    }
  }
}

// ---------------------------------------------------------------------------
__global__ __launch_bounds__(256) void cast_bf16_k(
    const float* __restrict__ src, __hip_bfloat16* __restrict__ dst, int n4) {
  int i = xcdswz_(blockIdx.x, gridDim.x) * 256 + threadIdx.x;
  if (i >= n4) return;
  float4 v = reinterpret_cast<const float4*>(src)[i];
  union { __hip_bfloat16 h[4]; short4 s4; } u;
  u.h[0] = __float2bfloat16(v.x); u.h[1] = __float2bfloat16(v.y);
  u.h[2] = __float2bfloat16(v.z); u.h[3] = __float2bfloat16(v.w);
  reinterpret_cast<short4*>(dst)[i] = u.s4;
}

__global__ __launch_bounds__(256) void pad_wx_k(
    const float* __restrict__ src, __hip_bfloat16* __restrict__ dst) {
  int i = blockIdx.x * 256 + threadIdx.x;
  int row = i >> 7;
  union { __hip_bfloat16 h[4]; short4 s4; } u;
  if (row < 48) {
    float4 v = reinterpret_cast<const float4*>(src)[i];
    u.h[0] = __float2bfloat16(v.x); u.h[1] = __float2bfloat16(v.y);
    u.h[2] = __float2bfloat16(v.z); u.h[3] = __float2bfloat16(v.w);
  } else {
    u.h[0] = u.h[1] = u.h[2] = u.h[3] = __float2bfloat16(0.f);
  }
  reinterpret_cast<short4*>(dst)[i] = u.s4;
}

// ---------------------------------------------------------------------------
// Depthwise causal conv (D_CONV=4) + SiLU, 2 rows/thread (windows overlap:
// 5 int4 loads produce 2 output rows). In: xz (rows,1024) cols 0..511.
// Row pairs (2rp, 2rp+1) never straddle a batch boundary (SEQ even).
// ---------------------------------------------------------------------------
__global__ __launch_bounds__(256) void conv_silu_k(
    const __hip_bfloat16* __restrict__ xz, const float* __restrict__ cw,
    const float* __restrict__ cb, __hip_bfloat16* __restrict__ xi) {
  int idx = xcdswz_(blockIdx.x, gridDim.x) * 256 + threadIdx.x;  // rp*64 + t
  int t = idx & 63;
  int rp = idx >> 6;
  int r = rp << 1;
  int l = r & (SEQ - 1);   // even; l+1 stays in-batch
  int c8 = t << 3;
  const __hip_bfloat16* p = xz + (size_t)r * 1024 + c8;
  union U8 { int4 v; __hip_bfloat16 h[8]; } x0, x1, x2, x3, x4, oa, ob;
  const int4 z4 = make_int4(0, 0, 0, 0);
  x4.v = *reinterpret_cast<const int4*>(p + 1024);
  x3.v = *reinterpret_cast<const int4*>(p);
  x2.v = (l >= 1) ? *reinterpret_cast<const int4*>(p - 1024) : z4;
  x1.v = (l >= 2) ? *reinterpret_cast<const int4*>(p - 2048) : z4;
  x0.v = (l >= 3) ? *reinterpret_cast<const int4*>(p - 3072) : z4;
  const float4* cw4 = reinterpret_cast<const float4*>(cw);
#pragma unroll
  for (int j = 0; j < 8; ++j) {
    float4 w = cw4[c8 + j];
    float b = cb[c8 + j];
    float f0 = __bfloat162float(x0.h[j]);
    float f1 = __bfloat162float(x1.h[j]);
    float f2 = __bfloat162float(x2.h[j]);
    float f3 = __bfloat162float(x3.h[j]);
    float f4 = __bfloat162float(x4.h[j]);
    float a0 = fmaf(w.w, f3, fmaf(w.z, f2, fmaf(w.y, f1, fmaf(w.x, f0, b))));
    float a1 = fmaf(w.w, f4, fmaf(w.z, f3, fmaf(w.y, f2, fmaf(w.x, f1, b))));
    oa.h[j] = __float2bfloat16(silu_(a0));
    ob.h[j] = __float2bfloat16(silu_(a1));
  }
  *reinterpret_cast<int4*>(&xi[(size_t)r * 512 + c8]) = oa.v;
  *reinterpret_cast<int4*>(&xi[(size_t)(r + 1) * 512 + c8]) = ob.v;
}

// ---------------------------------------------------------------------------
// Chunked selective scan (R11 form: reads xi; deltab bf16; hp bf16; dlsum).
// ---------------------------------------------------------------------------
__global__ __launch_bounds__(256) void scan_p1(
    const __hip_bfloat16* __restrict__ u, const float* __restrict__ xdbl,
    const float* __restrict__ A_log, const float* __restrict__ wdt,
    const float* __restrict__ bdt, float* __restrict__ dlsum,
    __hip_bfloat16* __restrict__ hp, __hip_bfloat16* __restrict__ deltab) {
  const int w = xcdswz_(blockIdx.x, gridDim.x);  // b*128 + c*2 + h
  const int b = w >> 7;
  const int c = (w >> 1) & 63;
  const int d = ((w & 1) << 8) + threadIdx.x;
  const int l0 = c * CHL;
  float A2[16];
  f32x2 w2[8];
  {
    const float4* aq = reinterpret_cast<const float4*>(&A_log[d * 16]);
    const f32x2* wq = reinterpret_cast<const f32x2*>(&wdt[d * 16]);
#pragma unroll
    for (int q = 0; q < 4; ++q) {
      float4 v = aq[q];
      A2[q * 4 + 0] = -exp2_(v.x * L2E) * L2E;
      A2[q * 4 + 1] = -exp2_(v.y * L2E) * L2E;
      A2[q * 4 + 2] = -exp2_(v.z * L2E) * L2E;
      A2[q * 4 + 3] = -exp2_(v.w * L2E) * L2E;
    }
#pragma unroll
    for (int k = 0; k < 8; ++k) w2[k] = wq[k];
  }
  bool chainok = true;
#pragma unroll
  for (int n = 1; n < 16; ++n)
    chainok = chainok &&
              (fabsf(A2[n] - (float)(n + 1) * A2[0]) <=
               1e-4f * (float)(n + 1) * fabsf(A2[0]));
  const float bdtd = bdt[d];
  const float nL = A2[0];
  f32x2 h2[8];
#pragma unroll
  for (int k = 0; k < 8; ++k) h2[k] = (f32x2){0.f, 0.f};
  float dls = 0.f;
  size_t base = (size_t)(b * SEQ + l0) * 512 + d;
  const float* rowp = xdbl + (size_t)(b * SEQ + l0) * 48;
  if (chainok) {
#pragma unroll 4
    for (int i = 0; i < CHL; ++i) {
      const f32x2* r2 = reinterpret_cast<const f32x2*>(rowp + i * 48);
      f32x2 acc2; acc2.x = bdtd; acc2.y = 0.f;
#pragma unroll
      for (int k = 0; k < 8; ++k)
        acc2 = __builtin_elementwise_fma(r2[k], w2[k], acc2);
      float dl = softplus_(acc2.x + acc2.y);
      deltab[base + (size_t)i * 512] = __float2bfloat16(dl);
      dls += dl;
      float du = dl * __bfloat162float(u[base + (size_t)i * 512]);
      f32x2 p[8];
      powpairs_(exp2_(dl * nL), p);
      f32x2 du2; du2.x = du; du2.y = du;
#pragma unroll
      for (int k = 0; k < 8; ++k)
        h2[k] = __builtin_elementwise_fma(p[k], h2[k], du2 * r2[8 + k]);
    }
  } else {
#pragma unroll 2
    for (int i = 0; i < CHL; ++i) {
      const f32x2* r2 = reinterpret_cast<const f32x2*>(rowp + i * 48);
      f32x2 acc2; acc2.x = bdtd; acc2.y = 0.f;
#pragma unroll
      for (int k = 0; k < 8; ++k)
        acc2 = __builtin_elementwise_fma(r2[k], w2[k], acc2);
      float dl = softplus_(acc2.x + acc2.y);
      deltab[base + (size_t)i * 512] = __float2bfloat16(dl);
      dls += dl;
      float du = dl * __bfloat162float(u[base + (size_t)i * 512]);
      f32x2 du2; du2.x = du; du2.y = du;
#pragma unroll
      for (int k = 0; k < 8; ++k) {
        f32x2 a; a.x = exp2_(dl * A2[2 * k]); a.y = exp2_(dl * A2[2 * k + 1]);
        h2[k] = __builtin_elementwise_fma(a, h2[k], du2 * r2[8 + k]);
      }
    }
  }
  size_t sc = (size_t)(b * NCH + c) * 512 + d;
  dlsum[sc] = dls;
  union { __hip_bfloat16 h[4]; short4 s4; } o0, o1, o2, o3;
#pragma unroll
  for (int j = 0; j < 2; ++j) {
    o0.h[2*j] = __float2bfloat16(h2[j].x);   o0.h[2*j+1] = __float2bfloat16(h2[j].y);
    o1.h[2*j] = __float2bfloat16(h2[2+j].x); o1.h[2*j+1] = __float2bfloat16(h2[2+j].y);
    o2.h[2*j] = __float2bfloat16(h2[4+j].x); o2.h[2*j+1] = __float2bfloat16(h2[4+j].y);
    o3.h[2*j] = __float2bfloat16(h2[6+j].x); o3.h[2*j+1] = __float2bfloat16(h2[6+j].y);
  }
  short4* hq = reinterpret_cast<short4*>(hp + sc * 16);
  hq[0] = o0.s4; hq[1] = o1.s4; hq[2] = o2.s4; hq[3] = o3.s4;
}

// In-place: Hc overwrites hp (in-thread read-before-write per idx).
__global__ __launch_bounds__(256) void scan_p2(
    __hip_bfloat16* hp, const float* __restrict__ dlsum,
    const float* __restrict__ A_log) {
  int g = xcdswz_(blockIdx.x, gridDim.x) * 256 + threadIdx.x;
  int b = g >> 13;
  int dn = g & 8191;
  int d = dn >> 4;
  float A2n = -exp2_(A_log[dn] * L2E) * L2E;
  float H = 0.f;
  for (int c = 0; c < NCH; ++c) {
    float ds = dlsum[(size_t)(b * NCH + c) * 512 + d];
    size_t idx = (size_t)(b * NCH + c) * 8192 + dn;
    float p = __bfloat162float(hp[idx]);
    float a = exp2_(A2n * ds);
    hp[idx] = __float2bfloat16(H);
    H = fmaf(a, H, p);
  }
}

__global__ __launch_bounds__(256) void scan_p3(
    const __hip_bfloat16* u,  // aliases y (same-thread read-before-write)
    const float* __restrict__ A_log,
    const __hip_bfloat16* __restrict__ deltab, const float* __restrict__ xdbl,
    const __hip_bfloat16* __restrict__ Hc, const float* __restrict__ Dp,
    const __hip_bfloat16* __restrict__ xz, __hip_bfloat16* y) {
  const int w = xcdswz_(blockIdx.x, gridDim.x);
  const int b = w >> 7;
  const int c = (w >> 1) & 63;
  const int d = ((w & 1) << 8) + threadIdx.x;
  const int l0 = c * CHL;
  float A2[16];
  {
    const float4* aq = reinterpret_cast<const float4*>(&A_log[d * 16]);
#pragma unroll
    for (int q = 0; q < 4; ++q) {
      float4 v = aq[q];
      A2[q * 4 + 0] = -exp2_(v.x * L2E) * L2E;
      A2[q * 4 + 1] = -exp2_(v.y * L2E) * L2E;
      A2[q * 4 + 2] = -exp2_(v.z * L2E) * L2E;
      A2[q * 4 + 3] = -exp2_(v.w * L2E) * L2E;
    }
  }
  bool chainok = true;
#pragma unroll
  for (int n = 1; n < 16; ++n)
    chainok = chainok &&
              (fabsf(A2[n] - (float)(n + 1) * A2[0]) <=
               1e-4f * (float)(n + 1) * fabsf(A2[0]));
  const float nL = A2[0];
  f32x2 h2[8];
  {
    const short4* hq =
        reinterpret_cast<const short4*>(Hc + ((size_t)(b * NCH + c) * 512 + d) * 16);
#pragma unroll
    for (int q = 0; q < 4; ++q) {
      union { short4 s4; __hip_bfloat16 h[4]; } iv;
      iv.s4 = hq[q];
      h2[2*q].x = __bfloat162float(iv.h[0]);
      h2[2*q].y = __bfloat162float(iv.h[1]);
      h2[2*q+1].x = __bfloat162float(iv.h[2]);
      h2[2*q+1].y = __bfloat162float(iv.h[3]);
    }
  }
  const float Dpd = Dp[d];
  size_t base = (size_t)(b * SEQ + l0) * 512 + d;
  const float* rowp = xdbl + (size_t)(b * SEQ + l0) * 48;
  const __hip_bfloat16* zp = xz + (size_t)(b * SEQ + l0) * 1024 + 512 + d;
  if (chainok) {
#pragma unroll 4
    for (int i = 0; i < CHL; ++i) {
      const f32x2* r2 = reinterpret_cast<const f32x2*>(rowp + i * 48);
      float dl = __bfloat162float(deltab[base + (size_t)i * 512]);
      float ul = __bfloat162float(u[base + (size_t)i * 512]);
      float du = dl * ul;
      f32x2 p[8];
      powpairs_(exp2_(dl * nL), p);
      f32x2 du2; du2.x = du; du2.y = du;
      f32x2 yv2; yv2.x = 0.f; yv2.y = 0.f;
#pragma unroll
      for (int k = 0; k < 8; ++k) {
        h2[k] = __builtin_elementwise_fma(p[k], h2[k], du2 * r2[8 + k]);
        yv2 = __builtin_elementwise_fma(h2[k], r2[16 + k], yv2);
      }
      float yv = yv2.x + yv2.y;
      float zv = __bfloat162float(zp[(size_t)i * 1024]);
      y[base + (size_t)i * 512] =
          __float2bfloat16((yv + ul * Dpd) * silu_(zv));
    }
  } else {
#pragma unroll 2
    for (int i = 0; i < CHL; ++i) {
      const f32x2* r2 = reinterpret_cast<const f32x2*>(rowp + i * 48);
      float dl = __bfloat162float(deltab[base + (size_t)i * 512]);
      float ul = __bfloat162float(u[base + (size_t)i * 512]);
      float du = dl * ul;
      f32x2 du2; du2.x = du; du2.y = du;
      f32x2 yv2; yv2.x = 0.f; yv2.y = 0.f;
#pragma unroll
      for (int k = 0; k < 8; ++k) {
        f32x2 a; a.x = exp2_(dl * A2[2 * k]); a.y = exp2_(dl * A2[2 * k + 1]);
        h2[k] = __builtin_elementwise_fma(a, h2[k], du2 * r2[8 + k]);
        yv2 = __builtin_elementwise_fma(h2[k], r2[16 + k], yv2);
      }
      float yv = yv2.x + yv2.y;
      float zv = __bfloat162float(zp[(size_t)i * 1024]);
      y[base + (size_t)i * 512] =
          __float2bfloat16((yv + ul * Dpd) * silu_(zv));
    }
  }
}

// ---------------------------------------------------------------------------
__global__ __launch_bounds__(256) void ln_k(
    const __hip_bfloat16* __restrict__ in, const float* __restrict__ g,
    const float* __restrict__ bb, __hip_bfloat16* __restrict__ outb) {
  int row = (xcdswz_(blockIdx.x, gridDim.x) * 256 + threadIdx.x) >> 6;
  int lane = threadIdx.x & 63;
  union { short4 s4; __hip_bfloat16 h[4]; } iv;
  iv.s4 = reinterpret_cast<const short4*>(in)[row * 64 + lane];
  float v0 = __bfloat162float(iv.h[0]), v1 = __bfloat162float(iv.h[1]);
  float v2 = __bfloat162float(iv.h[2]), v3 = __bfloat162float(iv.h[3]);
  float mu = wsum_(v0 + v1 + v2 + v3) * (1.f / 256.f);
  float a0 = v0 - mu, a1 = v1 - mu, a2 = v2 - mu, a3 = v3 - mu;
  float var = wsum_(a0 * a0 + a1 * a1 + a2 * a2 + a3 * a3) * (1.f / 256.f);
  float rs = __builtin_amdgcn_rsqf(var + 1e-5f);
  float4 gg = *reinterpret_cast<const float4*>(&g[lane * 4]);
  float4 bq = *reinterpret_cast<const float4*>(&bb[lane * 4]);
  union { __hip_bfloat16 h[4]; short4 s4; } u;
  u.h[0] = __float2bfloat16(a0 * rs * gg.x + bq.x);
  u.h[1] = __float2bfloat16(a1 * rs * gg.y + bq.y);
  u.h[2] = __float2bfloat16(a2 * rs * gg.z + bq.z);
  u.h[3] = __float2bfloat16(a3 * rs * gg.w + bq.w);
  reinterpret_cast<short4*>(outb)[row * 64 + lane] = u.s4;
}

// ---------------------------------------------------------------------------
__global__ __launch_bounds__(256) void final_k(
    const __hip_bfloat16* __restrict__ t2, const float* __restrict__ g2v,
    const float* __restrict__ b2v, const float* __restrict__ g3v,
    const float* __restrict__ b3v, const float* __restrict__ x,
    float* __restrict__ out) {
  int bx = xcdswz_(blockIdx.x, gridDim.x);
  int half = bx & 1, nv = (bx >> 1) & 31, b = bx >> 6;
  int wave = threadIdx.x >> 6, lane = threadIdx.x & 63;
  __shared__ float sh[32][257];
  float4 gg2 = *reinterpret_cast<const float4*>(&g2v[lane * 4]);
  float4 bb2 = *reinterpret_cast<const float4*>(&b2v[lane * 4]);
  float4 gg3 = *reinterpret_cast<const float4*>(&g3v[lane * 4]);
  float4 bb3 = *reinterpret_cast<const float4*>(&b3v[lane * 4]);
#pragma unroll
  for (int i = 0; i < 8; ++i) {
    int pn = wave * 8 + i;
    int r = ((b * 32 + nv) << 6) + (half << 5) + pn;
    union { short4 s4; __hip_bfloat16 h[4]; } iv;
    iv.s4 = reinterpret_cast<const short4*>(t2)[r * 64 + lane];
    float v0 = __bfloat162float(iv.h[0]), v1 = __bfloat162float(iv.h[1]);
    float v2 = __bfloat162float(iv.h[2]), v3 = __bfloat162float(iv.h[3]);
    float mu = wsum_(v0 + v1 + v2 + v3) * (1.f / 256.f);
    float a0 = v0 - mu, a1 = v1 - mu, a2 = v2 - mu, a3 = v3 - mu;
    float var = wsum_(a0 * a0 + a1 * a1 + a2 * a2 + a3 * a3) * (1.f / 256.f);
    float rs = __builtin_amdgcn_rsqf(var + 1e-5f);
    a0 = a0 * rs * gg2.x + bb2.x; a1 = a1 * rs * gg2.y + bb2.y;
    a2 = a2 * rs * gg2.z + bb2.z; a3 = a3 * rs * gg2.w + bb2.w;
    mu = wsum_(a0 + a1 + a2 + a3) * (1.f / 256.f);
    float c0 = a0 - mu, c1 = a1 - mu, c2 = a2 - mu, c3 = a3 - mu;
    var = wsum_(c0 * c0 + c1 * c1 + c2 * c2 + c3 * c3) * (1.f / 256.f);
    rs = __builtin_amdgcn_rsqf(var + 1e-5f);
    sh[pn][lane * 4 + 0] = c0 * rs * gg3.x + bb3.x;
    sh[pn][lane * 4 + 1] = c1 * rs * gg3.y + bb3.y;
    sh[pn][lane * 4 + 2] = c2 * rs * gg3.z + bb3.z;
    sh[pn][lane * 4 + 3] = c3 * rs * gg3.w + bb3.w;
  }
  __syncthreads();
  int pnl = threadIdx.x & 31;
  int dbase = threadIdx.x >> 5;
  size_t obase = (size_t)((b * 32 + nv) * 256) * 64 + (half << 5) + pnl;
#pragma unroll
  for (int k = 0; k < 32; ++k) {
    int dd = dbase + (k << 3);
    size_t oi = obase + (size_t)dd * 64;
    out[oi] = sh[pnl][dd] + x[oi];
  }
}

// ---------------------------------------------------------------------------
extern "C" void kernel_launch(void* const* d_in, const int* in_sizes, int n_in,
                              void* d_out, int out_size, void* d_ws,
                              size_t ws_size, hipStream_t stream) {
  const float* x    = (const float*)d_in[0];
  const float* w_in = (const float*)d_in[1];
  const float* b_in = (const float*)d_in[2];
  const float* cw   = (const float*)d_in[3];
  const float* cb   = (const float*)d_in[4];
  const float* wx   = (const float*)d_in[5];
  const float* wdt  = (const float*)d_in[6];
  const float* bdt  = (const float*)d_in[7];
  const float* alog = (const float*)d_in[8];
  const float* Dp   = (const float*)d_in[9];
  const float* wout = (const float*)d_in[10];
  const float* g1   = (const float*)d_in[11];
  const float* b1   = (const float*)d_in[12];
  const float* wf1  = (const float*)d_in[13];
  const float* bf1  = (const float*)d_in[14];
  const float* wf2  = (const float*)d_in[15];
  const float* bf2  = (const float*)d_in[16];
  const float* g2   = (const float*)d_in[17];
  const float* b2   = (const float*)d_in[18];
  const float* g3   = (const float*)d_in[19];
  const float* b3   = (const float*)d_in[20];
  float* out = (float*)d_out;

  const size_t MB1 = 1048576;
  char* g = (char*)d_ws;
  __hip_bfloat16* wbf_in  = (__hip_bfloat16*)(g);              // 512 KB
  __hip_bfloat16* wbf_out = (__hip_bfloat16*)(g + 524288);     // 256 KB
  __hip_bfloat16* wbf_f1  = (__hip_bfloat16*)(g + 786432);     // 256 KB
  __hip_bfloat16* wbf_f2  = (__hip_bfloat16*)(g + 1048576);    // 256 KB
  __hip_bfloat16* wbf_xp  = (__hip_bfloat16*)(g + 1310720);    // 128 KB
  const size_t SHARED = 1572864;

  // Regions/batch: RA 4MB (xz|t2b) | RB 1MB (xbf|dlsum) | RC 2MB (xi|ffny)
  //   RD 384KB (xdbl) | RE 2MB (hp bf16 | resb+h1bf) | RF 2MB (deltab)
  const size_t PB = 11 * MB1 + 393216;  // 11,927,552 B/batch
  int nb = (int)((ws_size - SHARED) / PB);
  if (ws_size <= SHARED || nb < 1) return;
  if (nb > NBTOT) nb = NBTOT;

  dim3 blk(256);
  cast_bf16_k<<<dim3(256), blk, 0, stream>>>(w_in, wbf_in, 65536);
  cast_bf16_k<<<dim3(128), blk, 0, stream>>>(wout, wbf_out, 32768);
  cast_bf16_k<<<dim3(128), blk, 0, stream>>>(wf1, wbf_f1, 32768);
  cast_bf16_k<<<dim3(128), blk, 0, stream>>>(wf2, wbf_f2, 32768);
  pad_wx_k<<<dim3(64), blk, 0, stream>>>(wx, wbf_xp);

  for (int b0 = 0; b0 < NBTOT; b0 += nb) {
    int bn = (NBTOT - b0 < nb) ? (NBTOT - b0) : nb;
    char* base = g + SHARED;
    char* RA = base;                          // bn*4MB
    char* RB = base + (size_t)bn * 4 * MB1;   // bn*1MB
    char* RC = base + (size_t)bn * 5 * MB1;   // bn*2MB
    char* RD = base + (size_t)bn * 7 * MB1;   // bn*384KB
    char* RE = RD + (size_t)bn * 393216;      // bn*2MB
    char* RF = RE + (size_t)bn * 2 * MB1;     // bn*2MB

    __hip_bfloat16* xz     = (__hip_bfloat16*)RA;
    __hip_bfloat16* t2b    = (__hip_bfloat16*)RA;
    __hip_bfloat16* xbf    = (__hip_bfloat16*)RB;
    float*          dlsum  = (float*)RB;
    __hip_bfloat16* xibf   = (__hip_bfloat16*)RC;
    __hip_bfloat16* ffnybf = (__hip_bfloat16*)RC;
    float*          xdbl   = (float*)RD;
    __hip_bfloat16* hp     = (__hip_bfloat16*)RE;   // Hc in-place (bf16)
    __hip_bfloat16* resb   = (__hip_bfloat16*)RE;   // after scan
    __hip_bfloat16* h1bf   = (__hip_bfloat16*)(RE + (size_t)bn * MB1);
    __hip_bfloat16* deltab = (__hip_bfloat16*)RF;

    const float* xg = x + (size_t)b0 * SEQ * 256;
    float* outg = out + (size_t)b0 * SEQ * 256;
    int M = bn * SEQ;
    int MT = M / 128;

    cast_bf16_k<<<dim3(M * 64 / 256), blk, 0, stream>>>(xg, xbf, M * 64);
    // in_proj (N=1024, NT=8) -> xz bf16
    gemm_bf16<true, false, false, false, false, true, 3>
        <<<dim3(8 * MT), blk, 0, stream>>>(xbf, wbf_in, b_in, nullptr, nullptr,
                                           nullptr, xz, 1024, 256);
    conv_silu_k<<<dim3(M / 8), blk, 0, stream>>>(xz, cw, cb, xibf);
    // x_proj (N=48 padded, NT=1) -> xdbl f32
    gemm_bf16<false, false, false, false, true, false, 0>
        <<<dim3(MT), blk, 0, stream>>>(xibf, wbf_xp, nullptr, nullptr,
                                       nullptr, xdbl, nullptr, 48, 512);
    scan_p1<<<dim3(bn * 128), blk, 0, stream>>>(xibf, xdbl, alog, wdt, bdt,
                                                dlsum, hp, deltab);
    scan_p2<<<dim3(bn * 32), blk, 0, stream>>>(hp, dlsum, alog);
    scan_p3<<<dim3(bn * 128), blk, 0, stream>>>(xibf, alog, deltab, xdbl,
                                                hp, Dp, xz, xibf);
    // out_proj + residual(x f32) -> resb bf16 (N=256, NT=2)
    gemm_bf16<false, false, true, false, false, true, 1>
        <<<dim3(2 * MT), blk, 0, stream>>>(xibf, wbf_out, nullptr, xg, nullptr,
                                           nullptr, resb, 256, 512);
    ln_k<<<dim3(M / 4), blk, 0, stream>>>(resb, g1, b1, h1bf);
    // ffn1 + relu (N=512, NT=4) -> ffnybf
    gemm_bf16<true, true, false, false, false, true, 2>
        <<<dim3(4 * MT), blk, 0, stream>>>(h1bf, wbf_f1, bf1, nullptr, nullptr,
                                           nullptr, ffnybf, 512, 256);
    // ffn2 + bias + residual(h1 bf16) -> t2b bf16 (N=256, NT=2)
    gemm_bf16<true, false, false, true, false, true, 1>
        <<<dim3(2 * MT), blk, 0, stream>>>(ffnybf, wbf_f2, bf2, nullptr, h1bf,
                                           nullptr, t2b, 256, 512);
    final_k<<<dim3(bn * 64), blk, 0, stream>>>(t2b, g2, b2, g3, b3, xg, outg);
  }
}

// Round 15
// 259.174 us; speedup vs baseline: 1.1476x; 1.0046x over previous
//
#include <hip/hip_runtime.h>
#include <hip/hip_bf16.h>
#include <math.h>

#define SEQ    2048
#define NBTOT  16
#define NCH    64
#define CHL    32            // NCH*CHL == SEQ

#define L2E 1.4426950408889634f

typedef __attribute__((ext_vector_type(8))) __bf16 bf16x8;
typedef __attribute__((ext_vector_type(4))) float f32x4;
typedef __attribute__((ext_vector_type(2))) float f32x2;

#define GLOAD16(gp, lp)                                                   \
  __builtin_amdgcn_global_load_lds(                                       \
      (const __attribute__((address_space(1))) unsigned int*)(gp),        \
      (__attribute__((address_space(3))) unsigned int*)(lp), 16, 0, 0)

__device__ __forceinline__ float exp2_(float x) {
  return __builtin_amdgcn_exp2f(x);
}
__device__ __forceinline__ float silu_(float x) {
  return x * __builtin_amdgcn_rcpf(1.f + exp2_(-x * L2E));
}
__device__ __forceinline__ float softplus_(float x) {
  return fmaxf(x, 0.f) + __logf(1.f + exp2_(-fabsf(x) * L2E));
}
__device__ __forceinline__ float wsum_(float v) {
#pragma unroll
  for (int off = 32; off > 0; off >>= 1) v += __shfl_xor(v, off, 64);
  return v;
}
// Bijective XCD-chunk swizzle (nwg mult of 8) — pipeline-consistent row->XCD.
__device__ __forceinline__ int xcdswz_(int bid, int nwg) {
  return (bid & 7) * (nwg >> 3) + (bid >> 3);
}
// p[k] = {e1^(2k+1), e1^(2k+2)}: 2 squares + 7 pk_mul, depth 4
__device__ __forceinline__ void powpairs_(float e1, f32x2 p[8]) {
  float e2 = e1 * e1;
  f32x2 p0; p0.x = e1; p0.y = e2;
  f32x2 s2; s2.x = e2; s2.y = e2;
  f32x2 s4 = s2 * s2;
  f32x2 s8 = s4 * s4;
  p[0] = p0;      p[1] = p0 * s2; p[2] = p0 * s4; p[3] = p[1] * s4;
  p[4] = p0 * s8; p[5] = p[1] * s8; p[6] = p[2] * s8; p[7] = p[3] * s8;
}

// ---------------------------------------------------------------------------
// bf16 MFMA GEMM (m97 structure) + XCD-chunk swizzle + LDS-bounce epilogue.
// ---------------------------------------------------------------------------
template <bool BIAS, bool RELU, bool RES, bool RESB, bool F32OUT, bool BF16OUT,
          int NTLOG>
__global__ __launch_bounds__(256) void gemm_bf16(
    const __hip_bfloat16* __restrict__ A, const __hip_bfloat16* __restrict__ W,
    const float* __restrict__ bias, const float* __restrict__ res,
    const __hip_bfloat16* __restrict__ resb, float* __restrict__ C,
    __hip_bfloat16* __restrict__ Cb, int N, int K) {
  __shared__ __align__(16) char ShRaw[36864];
  short* Als = reinterpret_cast<short*>(ShRaw);
  short* Bls = Als + 8192;
  const int tid = threadIdx.x;
  const int lane = tid & 63;
  const int wid = tid >> 6;
  const int swz = xcdswz_(blockIdx.x, gridDim.x);
  const int m0 = (swz >> NTLOG) * 128;
  const int n0 = (swz & ((1 << NTLOG) - 1)) * 128;
  const int wm = (wid >> 1) * 64;
  const int wn = (wid & 1) * 64;
  const int lr = lane & 15;
  const int lk = lane >> 4;  // 0..3

  f32x4 acc[4][4];
#pragma unroll
  for (int m = 0; m < 4; ++m)
#pragma unroll
    for (int n = 0; n < 4; ++n) acc[m][n] = (f32x4){0.f, 0.f, 0.f, 0.f};

  const int srow = wid * 32 + (lane >> 3);
  const int scol = (lane & 7) * 8;
  const __hip_bfloat16* Ag = A + (size_t)(m0 + srow) * K + scol;
  const __hip_bfloat16* Wg = W + (size_t)(n0 + srow) * K + scol;
  short* Alb = Als + wid * 2048;
  short* Blb = Bls + wid * 2048;

  for (int kt = 0; kt < K; kt += 64) {
#pragma unroll
    for (int i = 0; i < 4; ++i) {
      GLOAD16(Ag + (size_t)(i * 8) * K + kt, Alb + i * 512);
      GLOAD16(Wg + (size_t)(i * 8) * K + kt, Blb + i * 512);
    }
    __syncthreads();
    const bf16x8* Af = reinterpret_cast<const bf16x8*>(Als);
    const bf16x8* Bf = reinterpret_cast<const bf16x8*>(Bls);
#pragma unroll
    for (int ks = 0; ks < 2; ++ks) {
      bf16x8 av[4], bv[4];
#pragma unroll
      for (int m = 0; m < 4; ++m)
        av[m] = Af[(wm + m * 16 + lr) * 8 + ks * 4 + lk];
#pragma unroll
      for (int n = 0; n < 4; ++n)
        bv[n] = Bf[(wn + n * 16 + lr) * 8 + ks * 4 + lk];
#pragma unroll
      for (int m = 0; m < 4; ++m)
#pragma unroll
        for (int n = 0; n < 4; ++n)
          acc[m][n] = __builtin_amdgcn_mfma_f32_16x16x32_bf16(
              av[m], bv[n], acc[m][n], 0, 0, 0);
    }
    __syncthreads();  // staging LDS dead after -> epilogue reuse
  }

  if (BF16OUT) {
    __hip_bfloat16* epi =
        reinterpret_cast<__hip_bfloat16*>(ShRaw) + wid * 4608;
#pragma unroll
    for (int n = 0; n < 4; ++n) {
      int col = n0 + wn + n * 16 + lr;
      float bval = BIAS ? bias[col] : 0.f;
#pragma unroll
      for (int m = 0; m < 4; ++m) {
        int lrow = m * 16 + lk * 4;
#pragma unroll
        for (int r = 0; r < 4; ++r) {
          float v = acc[m][n][r];
          if (BIAS) v += bval;
          if (RES) v += res[(size_t)(m0 + wm + lrow + r) * N + col];
          if (RESB)
            v += __bfloat162float(resb[(size_t)(m0 + wm + lrow + r) * N + col]);
          if (RELU) v = fmaxf(v, 0.f);
          epi[(lrow + r) * 72 + n * 16 + lr] = __float2bfloat16(v);
        }
      }
    }
    const int lr8 = (lane & 7) * 8;
    const int lrw = lane >> 3;
    const size_t obase = (size_t)(m0 + wm) * N + n0 + wn + lr8;
#pragma unroll
    for (int j = 0; j < 8; ++j) {
      int row = j * 8 + lrw;
      int4 vv = *reinterpret_cast<const int4*>(epi + row * 72 + lr8);
      *reinterpret_cast<int4*>(&Cb[obase + (size_t)row * N]) = vv;
    }
  }
  if (F32OUT) {
#pragma unroll
    for (int n = 0; n < 4; ++n) {
      int col = n0 + wn + n * 16 + lr;
      if (col >= N) continue;
      float bval = BIAS ? bias[col] : 0.f;
#pragma unroll
      for (int m = 0; m < 4; ++m) {
        int row0 = m0 + wm + m * 16 + lk * 4;
#pragma unroll
        for (int r = 0; r < 4; ++r) {
          size_t off = (size_t)(row0 + r) * N + col;
          float v = acc[m][n][r];
          if (BIAS) v += bval;
          if (RES) v += res[off];
          if (RESB) v += __bfloat162float(resb[off]);
          if (RELU) v = fmaxf(v, 0.f);
          C[off] = v;
        }
      }
    }
  }
}

// ---------------------------------------------------------------------------
__global__ __launch_bounds__(256) void cast_bf16_k(
    const float* __restrict__ src, __hip_bfloat16* __restrict__ dst, int n4) {
  int i = xcdswz_(blockIdx.x, gridDim.x) * 256 + threadIdx.x;
  if (i >= n4) return;
  float4 v = reinterpret_cast<const float4*>(src)[i];
  union { __hip_bfloat16 h[4]; short4 s4; } u;
  u.h[0] = __float2bfloat16(v.x); u.h[1] = __float2bfloat16(v.y);
  u.h[2] = __float2bfloat16(v.z); u.h[3] = __float2bfloat16(v.w);
  reinterpret_cast<short4*>(dst)[i] = u.s4;
}

__global__ __launch_bounds__(256) void pad_wx_k(
    const float* __restrict__ src, __hip_bfloat16* __restrict__ dst) {
  int i = blockIdx.x * 256 + threadIdx.x;
  int row = i >> 7;
  union { __hip_bfloat16 h[4]; short4 s4; } u;
  if (row < 48) {
    float4 v = reinterpret_cast<const float4*>(src)[i];
    u.h[0] = __float2bfloat16(v.x); u.h[1] = __float2bfloat16(v.y);
    u.h[2] = __float2bfloat16(v.z); u.h[3] = __float2bfloat16(v.w);
  } else {
    u.h[0] = u.h[1] = u.h[2] = u.h[3] = __float2bfloat16(0.f);
  }
  reinterpret_cast<short4*>(dst)[i] = u.s4;
}

// ---------------------------------------------------------------------------
// Depthwise causal conv (D_CONV=4) + SiLU, 2 rows/thread (windows overlap:
// 5 int4 loads produce 2 output rows). In: xz (rows,1024) cols 0..511.
// Row pairs (2rp, 2rp+1) never straddle a batch boundary (SEQ even).
// ---------------------------------------------------------------------------
__global__ __launch_bounds__(256) void conv_silu_k(
    const __hip_bfloat16* __restrict__ xz, const float* __restrict__ cw,
    const float* __restrict__ cb, __hip_bfloat16* __restrict__ xi) {
  int idx = xcdswz_(blockIdx.x, gridDim.x) * 256 + threadIdx.x;  // rp*64 + t
  int t = idx & 63;
  int rp = idx >> 6;
  int r = rp << 1;
  int l = r & (SEQ - 1);   // even; l+1 stays in-batch
  int c8 = t << 3;
  const __hip_bfloat16* p = xz + (size_t)r * 1024 + c8;
  union U8 { int4 v; __hip_bfloat16 h[8]; } x0, x1, x2, x3, x4, oa, ob;
  const int4 z4 = make_int4(0, 0, 0, 0);
  x4.v = *reinterpret_cast<const int4*>(p + 1024);
  x3.v = *reinterpret_cast<const int4*>(p);
  x2.v = (l >= 1) ? *reinterpret_cast<const int4*>(p - 1024) : z4;
  x1.v = (l >= 2) ? *reinterpret_cast<const int4*>(p - 2048) : z4;
  x0.v = (l >= 3) ? *reinterpret_cast<const int4*>(p - 3072) : z4;
  const float4* cw4 = reinterpret_cast<const float4*>(cw);
#pragma unroll
  for (int j = 0; j < 8; ++j) {
    float4 w = cw4[c8 + j];
    float b = cb[c8 + j];
    float f0 = __bfloat162float(x0.h[j]);
    float f1 = __bfloat162float(x1.h[j]);
    float f2 = __bfloat162float(x2.h[j]);
    float f3 = __bfloat162float(x3.h[j]);
    float f4 = __bfloat162float(x4.h[j]);
    float a0 = fmaf(w.w, f3, fmaf(w.z, f2, fmaf(w.y, f1, fmaf(w.x, f0, b))));
    float a1 = fmaf(w.w, f4, fmaf(w.z, f3, fmaf(w.y, f2, fmaf(w.x, f1, b))));
    oa.h[j] = __float2bfloat16(silu_(a0));
    ob.h[j] = __float2bfloat16(silu_(a1));
  }
  *reinterpret_cast<int4*>(&xi[(size_t)r * 512 + c8]) = oa.v;
  *reinterpret_cast<int4*>(&xi[(size_t)(r + 1) * 512 + c8]) = ob.v;
}

// ---------------------------------------------------------------------------
// Chunked selective scan (R11 form: reads xi; deltab bf16; hp bf16; dlsum).
// ---------------------------------------------------------------------------
__global__ __launch_bounds__(256) void scan_p1(
    const __hip_bfloat16* __restrict__ u, const float* __restrict__ xdbl,
    const float* __restrict__ A_log, const float* __restrict__ wdt,
    const float* __restrict__ bdt, float* __restrict__ dlsum,
    __hip_bfloat16* __restrict__ hp, __hip_bfloat16* __restrict__ deltab) {
  const int w = xcdswz_(blockIdx.x, gridDim.x);  // b*128 + c*2 + h
  const int b = w >> 7;
  const int c = (w >> 1) & 63;
  const int d = ((w & 1) << 8) + threadIdx.x;
  const int l0 = c * CHL;
  float A2[16];
  f32x2 w2[8];
  {
    const float4* aq = reinterpret_cast<const float4*>(&A_log[d * 16]);
    const f32x2* wq = reinterpret_cast<const f32x2*>(&wdt[d * 16]);
#pragma unroll
    for (int q = 0; q < 4; ++q) {
      float4 v = aq[q];
      A2[q * 4 + 0] = -exp2_(v.x * L2E) * L2E;
      A2[q * 4 + 1] = -exp2_(v.y * L2E) * L2E;
      A2[q * 4 + 2] = -exp2_(v.z * L2E) * L2E;
      A2[q * 4 + 3] = -exp2_(v.w * L2E) * L2E;
    }
#pragma unroll
    for (int k = 0; k < 8; ++k) w2[k] = wq[k];
  }
  bool chainok = true;
#pragma unroll
  for (int n = 1; n < 16; ++n)
    chainok = chainok &&
              (fabsf(A2[n] - (float)(n + 1) * A2[0]) <=
               1e-4f * (float)(n + 1) * fabsf(A2[0]));
  const float bdtd = bdt[d];
  const float nL = A2[0];
  f32x2 h2[8];
#pragma unroll
  for (int k = 0; k < 8; ++k) h2[k] = (f32x2){0.f, 0.f};
  float dls = 0.f;
  size_t base = (size_t)(b * SEQ + l0) * 512 + d;
  const float* rowp = xdbl + (size_t)(b * SEQ + l0) * 48;
  if (chainok) {
#pragma unroll 4
    for (int i = 0; i < CHL; ++i) {
      const f32x2* r2 = reinterpret_cast<const f32x2*>(rowp + i * 48);
      f32x2 acc2; acc2.x = bdtd; acc2.y = 0.f;
#pragma unroll
      for (int k = 0; k < 8; ++k)
        acc2 = __builtin_elementwise_fma(r2[k], w2[k], acc2);
      float dl = softplus_(acc2.x + acc2.y);
      deltab[base + (size_t)i * 512] = __float2bfloat16(dl);
      dls += dl;
      float du = dl * __bfloat162float(u[base + (size_t)i * 512]);
      f32x2 p[8];
      powpairs_(exp2_(dl * nL), p);
      f32x2 du2; du2.x = du; du2.y = du;
#pragma unroll
      for (int k = 0; k < 8; ++k)
        h2[k] = __builtin_elementwise_fma(p[k], h2[k], du2 * r2[8 + k]);
    }
  } else {
#pragma unroll 2
    for (int i = 0; i < CHL; ++i) {
      const f32x2* r2 = reinterpret_cast<const f32x2*>(rowp + i * 48);
      f32x2 acc2; acc2.x = bdtd; acc2.y = 0.f;
#pragma unroll
      for (int k = 0; k < 8; ++k)
        acc2 = __builtin_elementwise_fma(r2[k], w2[k], acc2);
      float dl = softplus_(acc2.x + acc2.y);
      deltab[base + (size_t)i * 512] = __float2bfloat16(dl);
      dls += dl;
      float du = dl * __bfloat162float(u[base + (size_t)i * 512]);
      f32x2 du2; du2.x = du; du2.y = du;
#pragma unroll
      for (int k = 0; k < 8; ++k) {
        f32x2 a; a.x = exp2_(dl * A2[2 * k]); a.y = exp2_(dl * A2[2 * k + 1]);
        h2[k] = __builtin_elementwise_fma(a, h2[k], du2 * r2[8 + k]);
      }
    }
  }
  size_t sc = (size_t)(b * NCH + c) * 512 + d;
  dlsum[sc] = dls;
  union { __hip_bfloat16 h[4]; short4 s4; } o0, o1, o2, o3;
#pragma unroll
  for (int j = 0; j < 2; ++j) {
    o0.h[2*j] = __float2bfloat16(h2[j].x);   o0.h[2*j+1] = __float2bfloat16(h2[j].y);
    o1.h[2*j] = __float2bfloat16(h2[2+j].x); o1.h[2*j+1] = __float2bfloat16(h2[2+j].y);
    o2.h[2*j] = __float2bfloat16(h2[4+j].x); o2.h[2*j+1] = __float2bfloat16(h2[4+j].y);
    o3.h[2*j] = __float2bfloat16(h2[6+j].x); o3.h[2*j+1] = __float2bfloat16(h2[6+j].y);
  }
  short4* hq = reinterpret_cast<short4*>(hp + sc * 16);
  hq[0] = o0.s4; hq[1] = o1.s4; hq[2] = o2.s4; hq[3] = o3.s4;
}

// In-place: Hc overwrites hp (in-thread read-before-write per idx).
__global__ __launch_bounds__(256) void scan_p2(
    __hip_bfloat16* hp, const float* __restrict__ dlsum,
    const float* __restrict__ A_log) {
  int g = xcdswz_(blockIdx.x, gridDim.x) * 256 + threadIdx.x;
  int b = g >> 13;
  int dn = g & 8191;
  int d = dn >> 4;
  float A2n = -exp2_(A_log[dn] * L2E) * L2E;
  float H = 0.f;
  for (int c = 0; c < NCH; ++c) {
    float ds = dlsum[(size_t)(b * NCH + c) * 512 + d];
    size_t idx = (size_t)(b * NCH + c) * 8192 + dn;
    float p = __bfloat162float(hp[idx]);
    float a = exp2_(A2n * ds);
    hp[idx] = __float2bfloat16(H);
    H = fmaf(a, H, p);
  }
}

__global__ __launch_bounds__(256) void scan_p3(
    const __hip_bfloat16* u,  // aliases y (same-thread read-before-write)
    const float* __restrict__ A_log,
    const __hip_bfloat16* __restrict__ deltab, const float* __restrict__ xdbl,
    const __hip_bfloat16* __restrict__ Hc, const float* __restrict__ Dp,
    const __hip_bfloat16* __restrict__ xz, __hip_bfloat16* y) {
  const int w = xcdswz_(blockIdx.x, gridDim.x);
  const int b = w >> 7;
  const int c = (w >> 1) & 63;
  const int d = ((w & 1) << 8) + threadIdx.x;
  const int l0 = c * CHL;
  float A2[16];
  {
    const float4* aq = reinterpret_cast<const float4*>(&A_log[d * 16]);
#pragma unroll
    for (int q = 0; q < 4; ++q) {
      float4 v = aq[q];
      A2[q * 4 + 0] = -exp2_(v.x * L2E) * L2E;
      A2[q * 4 + 1] = -exp2_(v.y * L2E) * L2E;
      A2[q * 4 + 2] = -exp2_(v.z * L2E) * L2E;
      A2[q * 4 + 3] = -exp2_(v.w * L2E) * L2E;
    }
  }
  bool chainok = true;
#pragma unroll
  for (int n = 1; n < 16; ++n)
    chainok = chainok &&
              (fabsf(A2[n] - (float)(n + 1) * A2[0]) <=
               1e-4f * (float)(n + 1) * fabsf(A2[0]));
  const float nL = A2[0];
  f32x2 h2[8];
  {
    const short4* hq =
        reinterpret_cast<const short4*>(Hc + ((size_t)(b * NCH + c) * 512 + d) * 16);
#pragma unroll
    for (int q = 0; q < 4; ++q) {
      union { short4 s4; __hip_bfloat16 h[4]; } iv;
      iv.s4 = hq[q];
      h2[2*q].x = __bfloat162float(iv.h[0]);
      h2[2*q].y = __bfloat162float(iv.h[1]);
      h2[2*q+1].x = __bfloat162float(iv.h[2]);
      h2[2*q+1].y = __bfloat162float(iv.h[3]);
    }
  }
  const float Dpd = Dp[d];
  size_t base = (size_t)(b * SEQ + l0) * 512 + d;
  const float* rowp = xdbl + (size_t)(b * SEQ + l0) * 48;
  const __hip_bfloat16* zp = xz + (size_t)(b * SEQ + l0) * 1024 + 512 + d;
  if (chainok) {
#pragma unroll 4
    for (int i = 0; i < CHL; ++i) {
      const f32x2* r2 = reinterpret_cast<const f32x2*>(rowp + i * 48);
      float dl = __bfloat162float(deltab[base + (size_t)i * 512]);
      float ul = __bfloat162float(u[base + (size_t)i * 512]);
      float du = dl * ul;
      f32x2 p[8];
      powpairs_(exp2_(dl * nL), p);
      f32x2 du2; du2.x = du; du2.y = du;
      f32x2 yv2; yv2.x = 0.f; yv2.y = 0.f;
#pragma unroll
      for (int k = 0; k < 8; ++k) {
        h2[k] = __builtin_elementwise_fma(p[k], h2[k], du2 * r2[8 + k]);
        yv2 = __builtin_elementwise_fma(h2[k], r2[16 + k], yv2);
      }
      float yv = yv2.x + yv2.y;
      float zv = __bfloat162float(zp[(size_t)i * 1024]);
      y[base + (size_t)i * 512] =
          __float2bfloat16((yv + ul * Dpd) * silu_(zv));
    }
  } else {
#pragma unroll 2
    for (int i = 0; i < CHL; ++i) {
      const f32x2* r2 = reinterpret_cast<const f32x2*>(rowp + i * 48);
      float dl = __bfloat162float(deltab[base + (size_t)i * 512]);
      float ul = __bfloat162float(u[base + (size_t)i * 512]);
      float du = dl * ul;
      f32x2 du2; du2.x = du; du2.y = du;
      f32x2 yv2; yv2.x = 0.f; yv2.y = 0.f;
#pragma unroll
      for (int k = 0; k < 8; ++k) {
        f32x2 a; a.x = exp2_(dl * A2[2 * k]); a.y = exp2_(dl * A2[2 * k + 1]);
        h2[k] = __builtin_elementwise_fma(a, h2[k], du2 * r2[8 + k]);
        yv2 = __builtin_elementwise_fma(h2[k], r2[16 + k], yv2);
      }
      float yv = yv2.x + yv2.y;
      float zv = __bfloat162float(zp[(size_t)i * 1024]);
      y[base + (size_t)i * 512] =
          __float2bfloat16((yv + ul * Dpd) * silu_(zv));
    }
  }
}

// ---------------------------------------------------------------------------
__global__ __launch_bounds__(256) void ln_k(
    const __hip_bfloat16* __restrict__ in, const float* __restrict__ g,
    const float* __restrict__ bb, __hip_bfloat16* __restrict__ outb) {
  int row = (xcdswz_(blockIdx.x, gridDim.x) * 256 + threadIdx.x) >> 6;
  int lane = threadIdx.x & 63;
  union { short4 s4; __hip_bfloat16 h[4]; } iv;
  iv.s4 = reinterpret_cast<const short4*>(in)[row * 64 + lane];
  float v0 = __bfloat162float(iv.h[0]), v1 = __bfloat162float(iv.h[1]);
  float v2 = __bfloat162float(iv.h[2]), v3 = __bfloat162float(iv.h[3]);
  float mu = wsum_(v0 + v1 + v2 + v3) * (1.f / 256.f);
  float a0 = v0 - mu, a1 = v1 - mu, a2 = v2 - mu, a3 = v3 - mu;
  float var = wsum_(a0 * a0 + a1 * a1 + a2 * a2 + a3 * a3) * (1.f / 256.f);
  float rs = __builtin_amdgcn_rsqf(var + 1e-5f);
  float4 gg = *reinterpret_cast<const float4*>(&g[lane * 4]);
  float4 bq = *reinterpret_cast<const float4*>(&bb[lane * 4]);
  union { __hip_bfloat16 h[4]; short4 s4; } u;
  u.h[0] = __float2bfloat16(a0 * rs * gg.x + bq.x);
  u.h[1] = __float2bfloat16(a1 * rs * gg.y + bq.y);
  u.h[2] = __float2bfloat16(a2 * rs * gg.z + bq.z);
  u.h[3] = __float2bfloat16(a3 * rs * gg.w + bq.w);
  reinterpret_cast<short4*>(outb)[row * 64 + lane] = u.s4;
}

// ---------------------------------------------------------------------------
__global__ __launch_bounds__(256) void final_k(
    const __hip_bfloat16* __restrict__ t2, const float* __restrict__ g2v,
    const float* __restrict__ b2v, const float* __restrict__ g3v,
    const float* __restrict__ b3v, const float* __restrict__ x,
    float* __restrict__ out) {
  int bx = xcdswz_(blockIdx.x, gridDim.x);
  int half = bx & 1, nv = (bx >> 1) & 31, b = bx >> 6;
  int wave = threadIdx.x >> 6, lane = threadIdx.x & 63;
  __shared__ float sh[32][257];
  float4 gg2 = *reinterpret_cast<const float4*>(&g2v[lane * 4]);
  float4 bb2 = *reinterpret_cast<const float4*>(&b2v[lane * 4]);
  float4 gg3 = *reinterpret_cast<const float4*>(&g3v[lane * 4]);
  float4 bb3 = *reinterpret_cast<const float4*>(&b3v[lane * 4]);
#pragma unroll
  for (int i = 0; i < 8; ++i) {
    int pn = wave * 8 + i;
    int r = ((b * 32 + nv) << 6) + (half << 5) + pn;
    union { short4 s4; __hip_bfloat16 h[4]; } iv;
    iv.s4 = reinterpret_cast<const short4*>(t2)[r * 64 + lane];
    float v0 = __bfloat162float(iv.h[0]), v1 = __bfloat162float(iv.h[1]);
    float v2 = __bfloat162float(iv.h[2]), v3 = __bfloat162float(iv.h[3]);
    float mu = wsum_(v0 + v1 + v2 + v3) * (1.f / 256.f);
    float a0 = v0 - mu, a1 = v1 - mu, a2 = v2 - mu, a3 = v3 - mu;
    float var = wsum_(a0 * a0 + a1 * a1 + a2 * a2 + a3 * a3) * (1.f / 256.f);
    float rs = __builtin_amdgcn_rsqf(var + 1e-5f);
    a0 = a0 * rs * gg2.x + bb2.x; a1 = a1 * rs * gg2.y + bb2.y;
    a2 = a2 * rs * gg2.z + bb2.z; a3 = a3 * rs * gg2.w + bb2.w;
    mu = wsum_(a0 + a1 + a2 + a3) * (1.f / 256.f);
    float c0 = a0 - mu, c1 = a1 - mu, c2 = a2 - mu, c3 = a3 - mu;
    var = wsum_(c0 * c0 + c1 * c1 + c2 * c2 + c3 * c3) * (1.f / 256.f);
    rs = __builtin_amdgcn_rsqf(var + 1e-5f);
    sh[pn][lane * 4 + 0] = c0 * rs * gg3.x + bb3.x;
    sh[pn][lane * 4 + 1] = c1 * rs * gg3.y + bb3.y;
    sh[pn][lane * 4 + 2] = c2 * rs * gg3.z + bb3.z;
    sh[pn][lane * 4 + 3] = c3 * rs * gg3.w + bb3.w;
  }
  __syncthreads();
  int pnl = threadIdx.x & 31;
  int dbase = threadIdx.x >> 5;
  size_t obase = (size_t)((b * 32 + nv) * 256) * 64 + (half << 5) + pnl;
#pragma unroll
  for (int k = 0; k < 32; ++k) {
    int dd = dbase + (k << 3);
    size_t oi = obase + (size_t)dd * 64;
    out[oi] = sh[pnl][dd] + x[oi];
  }
}

// ---------------------------------------------------------------------------
extern "C" void kernel_launch(void* const* d_in, const int* in_sizes, int n_in,
                              void* d_out, int out_size, void* d_ws,
                              size_t ws_size, hipStream_t stream) {
  const float* x    = (const float*)d_in[0];
  const float* w_in = (const float*)d_in[1];
  const float* b_in = (const float*)d_in[2];
  const float* cw   = (const float*)d_in[3];
  const float* cb   = (const float*)d_in[4];
  const float* wx   = (const float*)d_in[5];
  const float* wdt  = (const float*)d_in[6];
  const float* bdt  = (const float*)d_in[7];
  const float* alog = (const float*)d_in[8];
  const float* Dp   = (const float*)d_in[9];
  const float* wout = (const float*)d_in[10];
  const float* g1   = (const float*)d_in[11];
  const float* b1   = (const float*)d_in[12];
  const float* wf1  = (const float*)d_in[13];
  const float* bf1  = (const float*)d_in[14];
  const float* wf2  = (const float*)d_in[15];
  const float* bf2  = (const float*)d_in[16];
  const float* g2   = (const float*)d_in[17];
  const float* b2   = (const float*)d_in[18];
  const float* g3   = (const float*)d_in[19];
  const float* b3   = (const float*)d_in[20];
  float* out = (float*)d_out;

  const size_t MB1 = 1048576;
  char* g = (char*)d_ws;
  __hip_bfloat16* wbf_in  = (__hip_bfloat16*)(g);              // 512 KB
  __hip_bfloat16* wbf_out = (__hip_bfloat16*)(g + 524288);     // 256 KB
  __hip_bfloat16* wbf_f1  = (__hip_bfloat16*)(g + 786432);     // 256 KB
  __hip_bfloat16* wbf_f2  = (__hip_bfloat16*)(g + 1048576);    // 256 KB
  __hip_bfloat16* wbf_xp  = (__hip_bfloat16*)(g + 1310720);    // 128 KB
  const size_t SHARED = 1572864;

  // Regions/batch: RA 4MB (xz|t2b) | RB 1MB (xbf|dlsum) | RC 2MB (xi|ffny)
  //   RD 384KB (xdbl) | RE 2MB (hp bf16 | resb+h1bf) | RF 2MB (deltab)
  const size_t PB = 11 * MB1 + 393216;  // 11,927,552 B/batch
  int nb = (int)((ws_size - SHARED) / PB);
  if (ws_size <= SHARED || nb < 1) return;
  if (nb > NBTOT) nb = NBTOT;

  dim3 blk(256);
  cast_bf16_k<<<dim3(256), blk, 0, stream>>>(w_in, wbf_in, 65536);
  cast_bf16_k<<<dim3(128), blk, 0, stream>>>(wout, wbf_out, 32768);
  cast_bf16_k<<<dim3(128), blk, 0, stream>>>(wf1, wbf_f1, 32768);
  cast_bf16_k<<<dim3(128), blk, 0, stream>>>(wf2, wbf_f2, 32768);
  pad_wx_k<<<dim3(64), blk, 0, stream>>>(wx, wbf_xp);

  for (int b0 = 0; b0 < NBTOT; b0 += nb) {
    int bn = (NBTOT - b0 < nb) ? (NBTOT - b0) : nb;
    char* base = g + SHARED;
    char* RA = base;                          // bn*4MB
    char* RB = base + (size_t)bn * 4 * MB1;   // bn*1MB
    char* RC = base + (size_t)bn * 5 * MB1;   // bn*2MB
    char* RD = base + (size_t)bn * 7 * MB1;   // bn*384KB
    char* RE = RD + (size_t)bn * 393216;      // bn*2MB
    char* RF = RE + (size_t)bn * 2 * MB1;     // bn*2MB

    __hip_bfloat16* xz     = (__hip_bfloat16*)RA;
    __hip_bfloat16* t2b    = (__hip_bfloat16*)RA;
    __hip_bfloat16* xbf    = (__hip_bfloat16*)RB;
    float*          dlsum  = (float*)RB;
    __hip_bfloat16* xibf   = (__hip_bfloat16*)RC;
    __hip_bfloat16* ffnybf = (__hip_bfloat16*)RC;
    float*          xdbl   = (float*)RD;
    __hip_bfloat16* hp     = (__hip_bfloat16*)RE;   // Hc in-place (bf16)
    __hip_bfloat16* resb   = (__hip_bfloat16*)RE;   // after scan
    __hip_bfloat16* h1bf   = (__hip_bfloat16*)(RE + (size_t)bn * MB1);
    __hip_bfloat16* deltab = (__hip_bfloat16*)RF;

    const float* xg = x + (size_t)b0 * SEQ * 256;
    float* outg = out + (size_t)b0 * SEQ * 256;
    int M = bn * SEQ;
    int MT = M / 128;

    cast_bf16_k<<<dim3(M * 64 / 256), blk, 0, stream>>>(xg, xbf, M * 64);
    // in_proj (N=1024, NT=8) -> xz bf16
    gemm_bf16<true, false, false, false, false, true, 3>
        <<<dim3(8 * MT), blk, 0, stream>>>(xbf, wbf_in, b_in, nullptr, nullptr,
                                           nullptr, xz, 1024, 256);
    conv_silu_k<<<dim3(M / 8), blk, 0, stream>>>(xz, cw, cb, xibf);
    // x_proj (N=48 padded, NT=1) -> xdbl f32
    gemm_bf16<false, false, false, false, true, false, 0>
        <<<dim3(MT), blk, 0, stream>>>(xibf, wbf_xp, nullptr, nullptr,
                                       nullptr, xdbl, nullptr, 48, 512);
    scan_p1<<<dim3(bn * 128), blk, 0, stream>>>(xibf, xdbl, alog, wdt, bdt,
                                                dlsum, hp, deltab);
    scan_p2<<<dim3(bn * 32), blk, 0, stream>>>(hp, dlsum, alog);
    scan_p3<<<dim3(bn * 128), blk, 0, stream>>>(xibf, alog, deltab, xdbl,
                                                hp, Dp, xz, xibf);
    // out_proj + residual(x f32) -> resb bf16 (N=256, NT=2)
    gemm_bf16<false, false, true, false, false, true, 1>
        <<<dim3(2 * MT), blk, 0, stream>>>(xibf, wbf_out, nullptr, xg, nullptr,
                                           nullptr, resb, 256, 512);
    ln_k<<<dim3(M / 4), blk, 0, stream>>>(resb, g1, b1, h1bf);
    // ffn1 + relu (N=512, NT=4) -> ffnybf
    gemm_bf16<true, true, false, false, false, true, 2>
        <<<dim3(4 * MT), blk, 0, stream>>>(h1bf, wbf_f1, bf1, nullptr, nullptr,
                                           nullptr, ffnybf, 512, 256);
    // ffn2 + bias + residual(h1 bf16) -> t2b bf16 (N=256, NT=2)
    gemm_bf16<true, false, false, true, false, true, 1>
        <<<dim3(2 * MT), blk, 0, stream>>>(ffnybf, wbf_f2, bf2, nullptr, h1bf,
                                           nullptr, t2b, 256, 512);
    final_k<<<dim3(bn * 64), blk, 0, stream>>>(t2b, g2, b2, g3, b3, xg, outg);
  }
}